// Round 19
// baseline (224.651 us; speedup 1.0000x reference)
//
#include <hip/hip_runtime.h>
#include <math.h>

// ws float-offset layout (ws >= 1 GiB, we use ~56 MB):
// xavg  [0, 16384)
// xmax  [16384, 32768)
// ypart [32768, 294912)                16 slots x 16384: slot = c*4 + dquarter
// PD    [294912, +4194304)             delta^T   [c][b][chunk][d][t]  (64x64 tiles)
// PX    PD+4194304                     delta*xi^T
// PG    PX+4194304                     g^T  (silu(z)*wfold)
// BCB   PG+4194304 (+524288)           B [c][b][chunk][s][t]
// BCC   BCB+524288                     C [c][b][chunk][s][t]
// YB    BCC+524288 (+65536)            ybase [c][b][t]
#define OFF_YPART 32768
#define OFF_PD    294912
#define OFF_PX    (OFF_PD + 4194304)
#define OFF_PG    (OFF_PX + 4194304)
#define OFF_BCB   (OFF_PG + 4194304)
#define OFF_BCC   (OFF_BCB + 524288)
#define OFF_YB    (OFF_BCC + 524288)

__global__ __launch_bounds__(256) void kreduce(const float* __restrict__ in,
                                               float* __restrict__ xavg,
                                               float* __restrict__ xmax) {
    const int bl = blockIdx.x;            // 0..16383  (= b*512 + l)
    const float* p = in + (size_t)bl * 4096;
    const int t = threadIdx.x;
    float s = 0.f, m = -INFINITY;
#pragma unroll
    for (int it = 0; it < 4; ++it) {
        float4 v = *reinterpret_cast<const float4*>(p + (size_t)(it * 256 + t) * 4);
        s += v.x + v.y + v.z + v.w;
        m = fmaxf(m, fmaxf(fmaxf(v.x, v.y), fmaxf(v.z, v.w)));
    }
#pragma unroll
    for (int o = 1; o < 64; o <<= 1) {
        s += __shfl_xor(s, o);
        m = fmaxf(m, __shfl_xor(m, o));
    }
    __shared__ float ls[4], lm[4];
    const int w = t >> 6;
    if ((t & 63) == 0) { ls[w] = s; lm[w] = m; }
    __syncthreads();
    if (t == 0) {
        s = ls[0] + ls[1] + ls[2] + ls[3];
        m = fmaxf(fmaxf(lm[0], lm[1]), fmaxf(lm[2], lm[3]));
        xavg[bl] = s * (1.f / 4096.f);
        xmax[bl] = m;
    }
}

// slot of dbc j-index (j: 0,1=dt; 2..17=B; 18..33=C) in interleaved record
__device__ __forceinline__ int dbc_slot(int j) {
    return j < 2 ? j : (j < 18 ? 2 * j - 2 : 2 * j - 33);
}

// kprep: A-phases + full A3 precompute. (r11/r18 form — session optimum)
__global__ __launch_bounds__(512) void kprep(
    const float* __restrict__ xavg, const float* __restrict__ xmax,
    float* __restrict__ ws,
    const float* __restrict__ paw, const float* __restrict__ pab,
    const float* __restrict__ pmw, const float* __restrict__ pmb,
    const float* __restrict__ outw_outer,
    const float* __restrict__ f_in_w, const float* __restrict__ f_conv_w,
    const float* __restrict__ f_conv_b, const float* __restrict__ f_xproj_w,
    const float* __restrict__ f_dt_w, const float* __restrict__ f_dt_b,
    const float* __restrict__ f_D, const float* __restrict__ f_out_w,
    const float* __restrict__ b_in_w, const float* __restrict__ b_conv_w,
    const float* __restrict__ b_conv_b, const float* __restrict__ b_xproj_w,
    const float* __restrict__ b_dt_w, const float* __restrict__ b_dt_b,
    const float* __restrict__ b_D, const float* __restrict__ b_out_w)
{
    const int tid = threadIdx.x;
    const int c  = blockIdx.x >> 8;
    const int b  = (blockIdx.x >> 3) & 31;
    const int cq = blockIdx.x & 7;
    const int strm = c >> 1, dir = c & 1;

    const float* in_w = dir ? b_in_w   : f_in_w;
    const float* cwp  = dir ? b_conv_w : f_conv_w;
    const float* cbp  = dir ? b_conv_b : f_conv_b;
    const float* xpw  = dir ? b_xproj_w: f_xproj_w;
    const float* dtwp = dir ? b_dt_w   : f_dt_w;
    const float* dtbp = dir ? b_dt_b   : f_dt_b;
    const float* Dpar = dir ? b_D      : f_D;
    const float* owp  = dir ? b_out_w  : f_out_w;
    const float* projw = strm ? pmw : paw;
    const float* projb = strm ? pmb : pab;
    const float* xin   = strm ? xmax : xavg;

    __shared__ float sseq4[68];
    __shared__ float su[128], sv[128];
    __shared__ float scw[64][4], scb[64], sdtw[64][2], sdtb[64], sD[64], swf[64];
    __shared__ float sxp[34][68];
    __shared__ float sxi[64][68];
    __shared__ float sdbc[64][37];

    if (tid < 67) {
        int g = cq * 64 - 3 + tid;
        float val = 0.f;
        if (g >= 0) val = xin[b * 512 + (dir ? (511 - g) : g)];
        sseq4[tid] = val;
    }
    if (tid < 128) {
        float u = 0.f, v = 0.f;
        const float* row = in_w + tid * 32;
#pragma unroll
        for (int m = 0; m < 32; ++m) {
            u = fmaf(row[m], projw[m], u);
            v = fmaf(row[m], projb[m], v);
        }
        su[tid] = u; sv[tid] = v;
    }
    if (tid < 64) {
#pragma unroll
        for (int k = 0; k < 4; ++k) scw[tid][k] = cwp[tid * 4 + k];
        scb[tid] = cbp[tid];
        sdtw[tid][0] = dtwp[tid * 2];
        sdtw[tid][1] = dtwp[tid * 2 + 1];
        sdtb[tid] = dtbp[tid];
        sD[tid] = Dpar[tid];
        float wf = 0.f;
#pragma unroll
        for (int m = 0; m < 32; ++m) wf = fmaf(outw_outer[m], owp[m * 64 + tid], wf);
        swf[tid] = wf;
    }
    for (int i = tid; i < 34 * 64; i += 512) sxp[i >> 6][i & 63] = xpw[i];
    __syncthreads();

    const int ll8 = tid >> 3;
    const int j8  = tid & 7;
    const int gi  = cq * 64 + ll8;

    // A1: xi for all 64 d
    {
        float t0 = sseq4[ll8], t1 = sseq4[ll8 + 1], t2 = sseq4[ll8 + 2], t3 = sseq4[ll8 + 3];
        float vv0 = (gi >= 3) ? 1.f : 0.f;
        float vv1 = (gi >= 2) ? 1.f : 0.f;
        float vv2 = (gi >= 1) ? 1.f : 0.f;
#pragma unroll
        for (int k = 0; k < 8; ++k) {
            int di = j8 * 8 + k;
            float u = su[di], v = sv[di];
            float xc = scw[di][0] * fmaf(t0, u, vv0 * v)
                     + scw[di][1] * fmaf(t1, u, vv1 * v)
                     + scw[di][2] * fmaf(t2, u, vv2 * v)
                     + scw[di][3] * fmaf(t3, u, v);
            xc += scb[di];
            float sig = 1.f / (1.f + __expf(-xc));
            sxi[ll8][di] = xc * sig;
        }
    }
    __syncthreads();

    // A2: dbc = xi @ xproj_w.T (unroll 2: spill discipline, r2-r9 lesson)
    {
        float a0 = 0.f, a1 = 0.f, a2 = 0.f, a3 = 0.f, a4 = 0.f;
        const float4* xr4 = reinterpret_cast<const float4*>(&sxi[ll8][0]);
        const float4* r0 = reinterpret_cast<const float4*>(&sxp[j8 + 0][0]);
        const float4* r1 = reinterpret_cast<const float4*>(&sxp[j8 + 8][0]);
        const float4* r2 = reinterpret_cast<const float4*>(&sxp[j8 + 16][0]);
        const float4* r3 = reinterpret_cast<const float4*>(&sxp[j8 + 24][0]);
        const float4* r4 = (j8 < 2) ? reinterpret_cast<const float4*>(&sxp[j8 + 32][0]) : r0;
        bool extra = (j8 < 2);
#pragma unroll 2
        for (int q = 0; q < 16; ++q) {
            float4 x = xr4[q];
            float4 w;
            w = r0[q]; a0 = fmaf(x.x,w.x,fmaf(x.y,w.y,fmaf(x.z,w.z,fmaf(x.w,w.w,a0))));
            w = r1[q]; a1 = fmaf(x.x,w.x,fmaf(x.y,w.y,fmaf(x.z,w.z,fmaf(x.w,w.w,a1))));
            w = r2[q]; a2 = fmaf(x.x,w.x,fmaf(x.y,w.y,fmaf(x.z,w.z,fmaf(x.w,w.w,a2))));
            w = r3[q]; a3 = fmaf(x.x,w.x,fmaf(x.y,w.y,fmaf(x.z,w.z,fmaf(x.w,w.w,a3))));
            if (extra) { w = r4[q]; a4 = fmaf(x.x,w.x,fmaf(x.y,w.y,fmaf(x.z,w.z,fmaf(x.w,w.w,a4)))); }
        }
        sdbc[ll8][dbc_slot(j8)]      = a0;
        sdbc[ll8][dbc_slot(j8 + 8)]  = a1;
        sdbc[ll8][dbc_slot(j8 + 16)] = a2;
        sdbc[ll8][dbc_slot(j8 + 24)] = a3;
        if (extra) sdbc[ll8][dbc_slot(j8 + 32)] = a4;
    }
    __syncthreads();

    // A3: delta (softplus), delta*xi, g, ybase -> global transposed
    {
        const size_t tile = ((size_t)(c * 32 + b) * 8 + cq) * 4096;
        float dt0 = sdbc[ll8][0], dt1 = sdbc[ll8][1];
        float x3 = sseq4[ll8 + 3];
        float ybp = 0.f;
#pragma unroll 2
        for (int k = 0; k < 8; ++k) {
            int di = j8 * 8 + k;
            float xi = sxi[ll8][di];
            float pre = fmaf(dt0, sdtw[di][0], fmaf(dt1, sdtw[di][1], sdtb[di]));
            float sp = (pre > 20.f) ? pre : __logf(1.f + __expf(pre));
            float zv = fmaf(x3, su[64 + di], sv[64 + di]);
            float g = (zv / (1.f + __expf(-zv))) * swf[di];
            ws[OFF_PD + tile + di * 64 + ll8] = sp;
            ws[OFF_PX + tile + di * 64 + ll8] = sp * xi;
            ws[OFF_PG + tile + di * 64 + ll8] = g;
            ybp = fmaf(g * sD[di], xi, ybp);
        }
        ybp += __shfl_xor(ybp, 1);
        ybp += __shfl_xor(ybp, 2);
        ybp += __shfl_xor(ybp, 4);
        if (j8 == 0) ws[OFF_YB + (size_t)(c * 32 + b) * 512 + gi] = ybp;
    }

    // B/C copy -> [s][t] layout (coalesced over t)
    {
        const size_t bb = ((size_t)(c * 32 + b) * 8 + cq) * 1024;
        for (int i = tid; i < 1024; i += 512) {
            int s = i >> 6, t = i & 63;
            ws[OFF_BCB + bb + i] = sdbc[t][2 + 2 * s];
            ws[OFF_BCC + bb + i] = sdbc[t][3 + 2 * s];
        }
    }
}

// DPP add over 16-lane rows: after shl 1,2,4,8, lane (s==0) holds the row sum.
#define DPP_ADD(v, ctrl) ((v) + __int_as_float(__builtin_amdgcn_update_dpp(0, __float_as_int(v), (ctrl), 0xF, 0xF, true)))

// kscan: pure scan. One block per (c, dquarter, b): 512 blocks x 256 threads.
// ROUND 19: launched 3x (idempotent: reads PD/PX/PG/BC/YB, writes only ypart)
// as a replication diagnostic — dur - 126.1 = 2 x kscan. The 1 GiB harness
// fills mask all our kernels out of the rocprof top-5, so this is the only
// per-kernel attribution available.
__global__ __launch_bounds__(256) void kscan(
    float* __restrict__ ws,
    const float* __restrict__ f_A_log, const float* __restrict__ b_A_log)
{
    const int tid = threadIdx.x;
    const int c  = blockIdx.x >> 7;
    const int dq = (blockIdx.x >> 5) & 3;
    const int b  = blockIdx.x & 31;
    const int dir = c & 1;
    const float* alog = dir ? b_A_log : f_A_log;

    const int dd = tid >> 4;
    const int s  = tid & 15;
    const int d  = dq * 16 + dd;
    const float cA = -expf(alog[d * 16 + s]) * 1.44269504088896340736f;
    float h = 0.f;

    __shared__ float sd[16][68], sx[16][68], sg[16][68];
    __shared__ float sB[16][68], sC[16][68];
    __shared__ float syT[16][68];
    __shared__ float syb[64];

    const int srow = tid >> 4;
    const int scol = (tid & 15) * 4;
    float* ypart = ws + OFF_YPART;

    for (int chunk = 0; chunk < 8; ++chunk) {
        const size_t tb = (size_t)(c * 32 + b) * 8 + chunk;
        const float* pd = ws + OFF_PD + tb * 4096 + dq * 1024;
        const float* px = ws + OFF_PX + tb * 4096 + dq * 1024;
        const float* pg = ws + OFF_PG + tb * 4096 + dq * 1024;
        const float* pB = ws + OFF_BCB + tb * 1024;
        const float* pC = ws + OFF_BCC + tb * 1024;

        *reinterpret_cast<float4*>(&sd[srow][scol]) =
            *reinterpret_cast<const float4*>(pd + srow * 64 + scol);
        *reinterpret_cast<float4*>(&sx[srow][scol]) =
            *reinterpret_cast<const float4*>(px + srow * 64 + scol);
        *reinterpret_cast<float4*>(&sg[srow][scol]) =
            *reinterpret_cast<const float4*>(pg + srow * 64 + scol);
        *reinterpret_cast<float4*>(&sB[srow][scol]) =
            *reinterpret_cast<const float4*>(pB + srow * 64 + scol);
        *reinterpret_cast<float4*>(&sC[srow][scol]) =
            *reinterpret_cast<const float4*>(pC + srow * 64 + scol);
        if (dq == 0 && tid < 64) syb[tid] = ws[OFF_YB + (size_t)(c * 32 + b) * 512 + chunk * 64 + tid];
        __syncthreads();

        {
#pragma unroll 2
            for (int m = 0; m < 16; ++m) {
                float4 de = *reinterpret_cast<const float4*>(&sd[dd][4 * m]);
                float4 dx = *reinterpret_cast<const float4*>(&sx[dd][4 * m]);
                float4 gq = *reinterpret_cast<const float4*>(&sg[dd][4 * m]);
                float4 Bq = *reinterpret_cast<const float4*>(&sB[s][4 * m]);
                float4 Cq = *reinterpret_cast<const float4*>(&sC[s][4 * m]);
                float4 val;
                float a, pc;
                a = exp2f(de.x * cA); h = fmaf(a, h, dx.x * Bq.x); pc = h * Cq.x;
                pc = DPP_ADD(pc, 0x101); pc = DPP_ADD(pc, 0x102);
                pc = DPP_ADD(pc, 0x104); pc = DPP_ADD(pc, 0x108);
                val.x = pc * gq.x;
                a = exp2f(de.y * cA); h = fmaf(a, h, dx.y * Bq.y); pc = h * Cq.y;
                pc = DPP_ADD(pc, 0x101); pc = DPP_ADD(pc, 0x102);
                pc = DPP_ADD(pc, 0x104); pc = DPP_ADD(pc, 0x108);
                val.y = pc * gq.y;
                a = exp2f(de.z * cA); h = fmaf(a, h, dx.z * Bq.z); pc = h * Cq.z;
                pc = DPP_ADD(pc, 0x101); pc = DPP_ADD(pc, 0x102);
                pc = DPP_ADD(pc, 0x104); pc = DPP_ADD(pc, 0x108);
                val.z = pc * gq.z;
                a = exp2f(de.w * cA); h = fmaf(a, h, dx.w * Bq.w); pc = h * Cq.w;
                pc = DPP_ADD(pc, 0x101); pc = DPP_ADD(pc, 0x102);
                pc = DPP_ADD(pc, 0x104); pc = DPP_ADD(pc, 0x108);
                val.w = pc * gq.w;
                if (s == 0) *reinterpret_cast<float4*>(&syT[dd][4 * m]) = val;
            }
        }
        __syncthreads();

        {
            const int tt4 = tid >> 2;
            const int j4  = tid & 3;
            float acc = syT[j4 * 4][tt4] + syT[j4 * 4 + 1][tt4]
                      + syT[j4 * 4 + 2][tt4] + syT[j4 * 4 + 3][tt4];
            acc += __shfl_xor(acc, 1);
            acc += __shfl_xor(acc, 2);
            if (j4 == 0) {
                int i = chunk * 64 + tt4;
                int l = dir ? (511 - i) : i;
                float res = acc + (dq == 0 ? syb[tt4] : 0.f);
                ypart[((c * 4 + dq) * 32 + b) * 512 + l] = res;
            }
        }
        __syncthreads();
    }
}

__global__ __launch_bounds__(256) void kfinal(const float* __restrict__ xavg,
                                              const float* __restrict__ xmax,
                                              const float* __restrict__ ypart,
                                              const float* __restrict__ gate_w,
                                              const float* __restrict__ gate_b,
                                              const float* __restrict__ out_b,
                                              float* __restrict__ out) {
    const int idx = blockIdx.x * 256 + threadIdx.x;
    float xa = xavg[idx], xm = xmax[idx];
    float alpha = 1.f / (1.f + __expf(-(fmaf(xa, gate_w[0], fmaf(xm, gate_w[1], gate_b[0])))));
    float sa = 0.f, sm = 0.f;
#pragma unroll
    for (int k = 0; k < 8; ++k)  sa += ypart[k * 16384 + idx];
#pragma unroll
    for (int k = 8; k < 16; ++k) sm += ypart[k * 16384 + idx];
    float y = alpha * sa + (1.f - alpha) * sm + out_b[0];
    out[idx] = 1.f / (1.f + __expf(-y));
}

extern "C" void kernel_launch(void* const* d_in, const int* in_sizes, int n_in,
                              void* d_out, int out_size, void* d_ws, size_t ws_size,
                              hipStream_t stream) {
    const float* inp = (const float*)d_in[0];
    const float* paw = (const float*)d_in[1];
    const float* pab = (const float*)d_in[2];
    const float* pmw = (const float*)d_in[3];
    const float* pmb = (const float*)d_in[4];
    const float* gw  = (const float*)d_in[5];
    const float* gb  = (const float*)d_in[6];
    const float* ow  = (const float*)d_in[7];
    const float* ob  = (const float*)d_in[8];

    float* ws = (float*)d_ws;
    float* xavg = ws;
    float* xmax = ws + 16384;
    float* ypart = ws + OFF_YPART;
    float* out = (float*)d_out;

    kreduce<<<16384, 256, 0, stream>>>(inp, xavg, xmax);
    kprep<<<1024, 512, 0, stream>>>(
        xavg, xmax, ws, paw, pab, pmw, pmb, ow,
        (const float*)d_in[9],  (const float*)d_in[10], (const float*)d_in[11], (const float*)d_in[12],
        (const float*)d_in[13], (const float*)d_in[14], (const float*)d_in[16], (const float*)d_in[17],
        (const float*)d_in[18], (const float*)d_in[19], (const float*)d_in[20], (const float*)d_in[21],
        (const float*)d_in[22], (const float*)d_in[23], (const float*)d_in[25], (const float*)d_in[26]);
    // DIAGNOSTIC: kscan launched 3x (idempotent). dur - 126.1 = 2 x kscan.
    for (int rep = 0; rep < 3; ++rep) {
        kscan<<<512, 256, 0, stream>>>(
            ws, (const float*)d_in[15], (const float*)d_in[24]);
    }
    kfinal<<<64, 256, 0, stream>>>(xavg, xmax, ypart, gw, gb, ob, out);
}

// Round 20
// 133.350 us; speedup vs baseline: 1.6847x; 1.6847x over previous
//
#include <hip/hip_runtime.h>
#include <math.h>

// ws float-offset layout (ws >= 1 GiB, we use ~56 MB):
// xavg  [0, 16384)
// xmax  [16384, 32768)
// ypart [32768, 163840)                8 slots x 16384: slot = c*2 + dhalf
// PD    [294912, +4194304)             delta^T   [c][b][chunk][d][t]  (64x64 tiles)
// PX    PD+4194304                     delta*xi^T
// PG    PX+4194304                     g^T  (silu(z)*wfold)
// BCB   PG+4194304 (+524288)           B [c][b][chunk][s][t]
// BCC   BCB+524288                     C [c][b][chunk][s][t]
// YB    BCC+524288 (+65536)            ybase [c][b][t]
#define OFF_YPART 32768
#define OFF_PD    294912
#define OFF_PX    (OFF_PD + 4194304)
#define OFF_PG    (OFF_PX + 4194304)
#define OFF_BCB   (OFF_PG + 4194304)
#define OFF_BCC   (OFF_BCB + 524288)
#define OFF_YB    (OFF_BCC + 524288)

__global__ __launch_bounds__(256) void kreduce(const float* __restrict__ in,
                                               float* __restrict__ xavg,
                                               float* __restrict__ xmax) {
    const int bl = blockIdx.x;            // 0..16383  (= b*512 + l)
    const float* p = in + (size_t)bl * 4096;
    const int t = threadIdx.x;
    float s = 0.f, m = -INFINITY;
#pragma unroll
    for (int it = 0; it < 4; ++it) {
        float4 v = *reinterpret_cast<const float4*>(p + (size_t)(it * 256 + t) * 4);
        s += v.x + v.y + v.z + v.w;
        m = fmaxf(m, fmaxf(fmaxf(v.x, v.y), fmaxf(v.z, v.w)));
    }
#pragma unroll
    for (int o = 1; o < 64; o <<= 1) {
        s += __shfl_xor(s, o);
        m = fmaxf(m, __shfl_xor(m, o));
    }
    __shared__ float ls[4], lm[4];
    const int w = t >> 6;
    if ((t & 63) == 0) { ls[w] = s; lm[w] = m; }
    __syncthreads();
    if (t == 0) {
        s = ls[0] + ls[1] + ls[2] + ls[3];
        m = fmaxf(fmaxf(lm[0], lm[1]), fmaxf(lm[2], lm[3]));
        xavg[bl] = s * (1.f / 4096.f);
        xmax[bl] = m;
    }
}

// slot of dbc j-index (j: 0,1=dt; 2..17=B; 18..33=C) in interleaved record
__device__ __forceinline__ int dbc_slot(int j) {
    return j < 2 ? j : (j < 18 ? 2 * j - 2 : 2 * j - 33);
}

// kprep: A-phases + full A3 precompute. (r11/r18 form — session optimum)
__global__ __launch_bounds__(512) void kprep(
    const float* __restrict__ xavg, const float* __restrict__ xmax,
    float* __restrict__ ws,
    const float* __restrict__ paw, const float* __restrict__ pab,
    const float* __restrict__ pmw, const float* __restrict__ pmb,
    const float* __restrict__ outw_outer,
    const float* __restrict__ f_in_w, const float* __restrict__ f_conv_w,
    const float* __restrict__ f_conv_b, const float* __restrict__ f_xproj_w,
    const float* __restrict__ f_dt_w, const float* __restrict__ f_dt_b,
    const float* __restrict__ f_D, const float* __restrict__ f_out_w,
    const float* __restrict__ b_in_w, const float* __restrict__ b_conv_w,
    const float* __restrict__ b_conv_b, const float* __restrict__ b_xproj_w,
    const float* __restrict__ b_dt_w, const float* __restrict__ b_dt_b,
    const float* __restrict__ b_D, const float* __restrict__ b_out_w)
{
    const int tid = threadIdx.x;
    const int c  = blockIdx.x >> 8;
    const int b  = (blockIdx.x >> 3) & 31;
    const int cq = blockIdx.x & 7;
    const int strm = c >> 1, dir = c & 1;

    const float* in_w = dir ? b_in_w   : f_in_w;
    const float* cwp  = dir ? b_conv_w : f_conv_w;
    const float* cbp  = dir ? b_conv_b : f_conv_b;
    const float* xpw  = dir ? b_xproj_w: f_xproj_w;
    const float* dtwp = dir ? b_dt_w   : f_dt_w;
    const float* dtbp = dir ? b_dt_b   : f_dt_b;
    const float* Dpar = dir ? b_D      : f_D;
    const float* owp  = dir ? b_out_w  : f_out_w;
    const float* projw = strm ? pmw : paw;
    const float* projb = strm ? pmb : pab;
    const float* xin   = strm ? xmax : xavg;

    __shared__ float sseq4[68];
    __shared__ float su[128], sv[128];
    __shared__ float scw[64][4], scb[64], sdtw[64][2], sdtb[64], sD[64], swf[64];
    __shared__ float sxp[34][68];
    __shared__ float sxi[64][68];
    __shared__ float sdbc[64][37];

    if (tid < 67) {
        int g = cq * 64 - 3 + tid;
        float val = 0.f;
        if (g >= 0) val = xin[b * 512 + (dir ? (511 - g) : g)];
        sseq4[tid] = val;
    }
    if (tid < 128) {
        float u = 0.f, v = 0.f;
        const float* row = in_w + tid * 32;
#pragma unroll
        for (int m = 0; m < 32; ++m) {
            u = fmaf(row[m], projw[m], u);
            v = fmaf(row[m], projb[m], v);
        }
        su[tid] = u; sv[tid] = v;
    }
    if (tid < 64) {
#pragma unroll
        for (int k = 0; k < 4; ++k) scw[tid][k] = cwp[tid * 4 + k];
        scb[tid] = cbp[tid];
        sdtw[tid][0] = dtwp[tid * 2];
        sdtw[tid][1] = dtwp[tid * 2 + 1];
        sdtb[tid] = dtbp[tid];
        sD[tid] = Dpar[tid];
        float wf = 0.f;
#pragma unroll
        for (int m = 0; m < 32; ++m) wf = fmaf(outw_outer[m], owp[m * 64 + tid], wf);
        swf[tid] = wf;
    }
    for (int i = tid; i < 34 * 64; i += 512) sxp[i >> 6][i & 63] = xpw[i];
    __syncthreads();

    const int ll8 = tid >> 3;
    const int j8  = tid & 7;
    const int gi  = cq * 64 + ll8;

    // A1: xi for all 64 d
    {
        float t0 = sseq4[ll8], t1 = sseq4[ll8 + 1], t2 = sseq4[ll8 + 2], t3 = sseq4[ll8 + 3];
        float vv0 = (gi >= 3) ? 1.f : 0.f;
        float vv1 = (gi >= 2) ? 1.f : 0.f;
        float vv2 = (gi >= 1) ? 1.f : 0.f;
#pragma unroll
        for (int k = 0; k < 8; ++k) {
            int di = j8 * 8 + k;
            float u = su[di], v = sv[di];
            float xc = scw[di][0] * fmaf(t0, u, vv0 * v)
                     + scw[di][1] * fmaf(t1, u, vv1 * v)
                     + scw[di][2] * fmaf(t2, u, vv2 * v)
                     + scw[di][3] * fmaf(t3, u, v);
            xc += scb[di];
            float sig = 1.f / (1.f + __expf(-xc));
            sxi[ll8][di] = xc * sig;
        }
    }
    __syncthreads();

    // A2: dbc = xi @ xproj_w.T (unroll 2: spill discipline, r2-r9 lesson)
    {
        float a0 = 0.f, a1 = 0.f, a2 = 0.f, a3 = 0.f, a4 = 0.f;
        const float4* xr4 = reinterpret_cast<const float4*>(&sxi[ll8][0]);
        const float4* r0 = reinterpret_cast<const float4*>(&sxp[j8 + 0][0]);
        const float4* r1 = reinterpret_cast<const float4*>(&sxp[j8 + 8][0]);
        const float4* r2 = reinterpret_cast<const float4*>(&sxp[j8 + 16][0]);
        const float4* r3 = reinterpret_cast<const float4*>(&sxp[j8 + 24][0]);
        const float4* r4 = (j8 < 2) ? reinterpret_cast<const float4*>(&sxp[j8 + 32][0]) : r0;
        bool extra = (j8 < 2);
#pragma unroll 2
        for (int q = 0; q < 16; ++q) {
            float4 x = xr4[q];
            float4 w;
            w = r0[q]; a0 = fmaf(x.x,w.x,fmaf(x.y,w.y,fmaf(x.z,w.z,fmaf(x.w,w.w,a0))));
            w = r1[q]; a1 = fmaf(x.x,w.x,fmaf(x.y,w.y,fmaf(x.z,w.z,fmaf(x.w,w.w,a1))));
            w = r2[q]; a2 = fmaf(x.x,w.x,fmaf(x.y,w.y,fmaf(x.z,w.z,fmaf(x.w,w.w,a2))));
            w = r3[q]; a3 = fmaf(x.x,w.x,fmaf(x.y,w.y,fmaf(x.z,w.z,fmaf(x.w,w.w,a3))));
            if (extra) { w = r4[q]; a4 = fmaf(x.x,w.x,fmaf(x.y,w.y,fmaf(x.z,w.z,fmaf(x.w,w.w,a4)))); }
        }
        sdbc[ll8][dbc_slot(j8)]      = a0;
        sdbc[ll8][dbc_slot(j8 + 8)]  = a1;
        sdbc[ll8][dbc_slot(j8 + 16)] = a2;
        sdbc[ll8][dbc_slot(j8 + 24)] = a3;
        if (extra) sdbc[ll8][dbc_slot(j8 + 32)] = a4;
    }
    __syncthreads();

    // A3: delta (softplus), delta*xi, g, ybase -> global transposed
    {
        const size_t tile = ((size_t)(c * 32 + b) * 8 + cq) * 4096;
        float dt0 = sdbc[ll8][0], dt1 = sdbc[ll8][1];
        float x3 = sseq4[ll8 + 3];
        float ybp = 0.f;
#pragma unroll 2
        for (int k = 0; k < 8; ++k) {
            int di = j8 * 8 + k;
            float xi = sxi[ll8][di];
            float pre = fmaf(dt0, sdtw[di][0], fmaf(dt1, sdtw[di][1], sdtb[di]));
            float sp = (pre > 20.f) ? pre : __logf(1.f + __expf(pre));
            float zv = fmaf(x3, su[64 + di], sv[64 + di]);
            float g = (zv / (1.f + __expf(-zv))) * swf[di];
            ws[OFF_PD + tile + di * 64 + ll8] = sp;
            ws[OFF_PX + tile + di * 64 + ll8] = sp * xi;
            ws[OFF_PG + tile + di * 64 + ll8] = g;
            ybp = fmaf(g * sD[di], xi, ybp);
        }
        ybp += __shfl_xor(ybp, 1);
        ybp += __shfl_xor(ybp, 2);
        ybp += __shfl_xor(ybp, 4);
        if (j8 == 0) ws[OFF_YB + (size_t)(c * 32 + b) * 512 + gi] = ybp;
    }

    // B/C copy -> [s][t] layout (coalesced over t)
    {
        const size_t bb = ((size_t)(c * 32 + b) * 8 + cq) * 1024;
        for (int i = tid; i < 1024; i += 512) {
            int s = i >> 6, t = i & 63;
            ws[OFF_BCB + bb + i] = sdbc[t][2 + 2 * s];
            ws[OFF_BCC + bb + i] = sdbc[t][3 + 2 * s];
        }
    }
}

// DPP add over 16-lane rows (row_shl). With shl 1,2,4: lane 0 of each 8-group
// (row positions 0 and 8) holds the sum of its 8-lane group.
#define DPP_ADD(v, ctrl) ((v) + __int_as_float(__builtin_amdgcn_update_dpp(0, __float_as_int(v), (ctrl), 0xF, 0xF, true)))

// kscan: pure scan, 2 s-states per thread.
// One block per (c, dhalf, b): 4*2*32 = 256 blocks x 256 threads.
// Thread (dd 0..31, s8 0..7) owns states s8 and s8+8: the 16-lane s-reduction
// becomes 1 local fma + 3 DPP (8-lane), cutting per-pair scan ops ~32% and
// doubling per-thread ILP (2 independent h chains) — the r19 diagnostic put
// kscan at 49us, dominated by DPP chain cost + latency exposure.
__global__ __launch_bounds__(256) void kscan(
    float* __restrict__ ws,
    const float* __restrict__ f_A_log, const float* __restrict__ b_A_log)
{
    const int tid = threadIdx.x;
    const int c  = blockIdx.x >> 6;
    const int dh = (blockIdx.x >> 5) & 1;
    const int b  = blockIdx.x & 31;
    const int dir = c & 1;
    const float* alog = dir ? b_A_log : f_A_log;

    const int dd = tid >> 3;          // 0..31 (local d in half)
    const int s8 = tid & 7;
    const int d  = dh * 32 + dd;      // global d 0..63
    const float cA0 = -expf(alog[d * 16 + s8])     * 1.44269504088896340736f;
    const float cA1 = -expf(alog[d * 16 + s8 + 8]) * 1.44269504088896340736f;
    float h0 = 0.f, h1 = 0.f;

    __shared__ float sd[32][68], sx[32][68], sg[32][68];
    __shared__ float sB[16][68], sC[16][68];
    __shared__ float syT[32][68];
    __shared__ float syb[64];

    const int row = tid >> 4;         // 0..15
    const int col = (tid & 15) * 4;
    float* ypart = ws + OFF_YPART;

    for (int chunk = 0; chunk < 8; ++chunk) {
        const size_t tb = (size_t)(c * 32 + b) * 8 + chunk;
        const float* pd = ws + OFF_PD + tb * 4096 + dh * 2048;   // [d][t], d-half
        const float* px = ws + OFF_PX + tb * 4096 + dh * 2048;
        const float* pg = ws + OFF_PG + tb * 4096 + dh * 2048;
        const float* pB = ws + OFF_BCB + tb * 1024;              // [s][t]
        const float* pC = ws + OFF_BCC + tb * 1024;

        // stage: 2 rows per P-array per thread, 1 row for B/C
        *reinterpret_cast<float4*>(&sd[row][col]) =
            *reinterpret_cast<const float4*>(pd + row * 64 + col);
        *reinterpret_cast<float4*>(&sd[row + 16][col]) =
            *reinterpret_cast<const float4*>(pd + (row + 16) * 64 + col);
        *reinterpret_cast<float4*>(&sx[row][col]) =
            *reinterpret_cast<const float4*>(px + row * 64 + col);
        *reinterpret_cast<float4*>(&sx[row + 16][col]) =
            *reinterpret_cast<const float4*>(px + (row + 16) * 64 + col);
        *reinterpret_cast<float4*>(&sg[row][col]) =
            *reinterpret_cast<const float4*>(pg + row * 64 + col);
        *reinterpret_cast<float4*>(&sg[row + 16][col]) =
            *reinterpret_cast<const float4*>(pg + (row + 16) * 64 + col);
        *reinterpret_cast<float4*>(&sB[row][col]) =
            *reinterpret_cast<const float4*>(pB + row * 64 + col);
        *reinterpret_cast<float4*>(&sC[row][col]) =
            *reinterpret_cast<const float4*>(pC + row * 64 + col);
        if (dh == 0 && tid < 64) syb[tid] = ws[OFF_YB + (size_t)(c * 32 + b) * 512 + chunk * 64 + tid];
        __syncthreads();

        // scan 16 m-iters x 4 steps; h0/h1 carried across chunks
        {
#pragma unroll 2
            for (int m = 0; m < 16; ++m) {
                float4 de = *reinterpret_cast<const float4*>(&sd[dd][4 * m]);
                float4 dx = *reinterpret_cast<const float4*>(&sx[dd][4 * m]);
                float4 gq = *reinterpret_cast<const float4*>(&sg[dd][4 * m]);
                float4 B0 = *reinterpret_cast<const float4*>(&sB[s8][4 * m]);
                float4 B1 = *reinterpret_cast<const float4*>(&sB[s8 + 8][4 * m]);
                float4 C0 = *reinterpret_cast<const float4*>(&sC[s8][4 * m]);
                float4 C1 = *reinterpret_cast<const float4*>(&sC[s8 + 8][4 * m]);
                float4 val;
                float a, pc;
                a = exp2f(de.x * cA0); h0 = fmaf(a, h0, dx.x * B0.x);
                a = exp2f(de.x * cA1); h1 = fmaf(a, h1, dx.x * B1.x);
                pc = fmaf(h0, C0.x, h1 * C1.x);
                pc = DPP_ADD(pc, 0x101); pc = DPP_ADD(pc, 0x102); pc = DPP_ADD(pc, 0x104);
                val.x = pc * gq.x;
                a = exp2f(de.y * cA0); h0 = fmaf(a, h0, dx.y * B0.y);
                a = exp2f(de.y * cA1); h1 = fmaf(a, h1, dx.y * B1.y);
                pc = fmaf(h0, C0.y, h1 * C1.y);
                pc = DPP_ADD(pc, 0x101); pc = DPP_ADD(pc, 0x102); pc = DPP_ADD(pc, 0x104);
                val.y = pc * gq.y;
                a = exp2f(de.z * cA0); h0 = fmaf(a, h0, dx.z * B0.z);
                a = exp2f(de.z * cA1); h1 = fmaf(a, h1, dx.z * B1.z);
                pc = fmaf(h0, C0.z, h1 * C1.z);
                pc = DPP_ADD(pc, 0x101); pc = DPP_ADD(pc, 0x102); pc = DPP_ADD(pc, 0x104);
                val.z = pc * gq.z;
                a = exp2f(de.w * cA0); h0 = fmaf(a, h0, dx.w * B0.w);
                a = exp2f(de.w * cA1); h1 = fmaf(a, h1, dx.w * B1.w);
                pc = fmaf(h0, C0.w, h1 * C1.w);
                pc = DPP_ADD(pc, 0x101); pc = DPP_ADD(pc, 0x102); pc = DPP_ADD(pc, 0x104);
                val.w = pc * gq.w;
                if (s8 == 0) *reinterpret_cast<float4*>(&syT[dd][4 * m]) = val;
            }
        }
        __syncthreads();

        // fold over 32 dd -> scalar partial into slot (c*2 + dh).
        // rows j4 + 4k: j4-lane bank offsets 68*j4 % 32 = 4*j4 -> conflict-free.
        {
            const int tt4 = tid >> 2;   // 0..63
            const int j4  = tid & 3;
            float acc = 0.f;
#pragma unroll
            for (int k = 0; k < 8; ++k) acc += syT[j4 + 4 * k][tt4];
            acc += __shfl_xor(acc, 1);
            acc += __shfl_xor(acc, 2);
            if (j4 == 0) {
                int i = chunk * 64 + tt4;
                int l = dir ? (511 - i) : i;
                float res = acc + (dh == 0 ? syb[tt4] : 0.f);
                ypart[((c * 2 + dh) * 32 + b) * 512 + l] = res;
            }
        }
        __syncthreads();
    }
}

__global__ __launch_bounds__(256) void kfinal(const float* __restrict__ xavg,
                                              const float* __restrict__ xmax,
                                              const float* __restrict__ ypart,
                                              const float* __restrict__ gate_w,
                                              const float* __restrict__ gate_b,
                                              const float* __restrict__ out_b,
                                              float* __restrict__ out) {
    const int idx = blockIdx.x * 256 + threadIdx.x;
    float xa = xavg[idx], xm = xmax[idx];
    float alpha = 1.f / (1.f + __expf(-(fmaf(xa, gate_w[0], fmaf(xm, gate_w[1], gate_b[0])))));
    float sa = 0.f, sm = 0.f;
#pragma unroll
    for (int k = 0; k < 4; ++k) sa += ypart[k * 16384 + idx];
#pragma unroll
    for (int k = 4; k < 8; ++k) sm += ypart[k * 16384 + idx];
    float y = alpha * sa + (1.f - alpha) * sm + out_b[0];
    out[idx] = 1.f / (1.f + __expf(-y));
}

extern "C" void kernel_launch(void* const* d_in, const int* in_sizes, int n_in,
                              void* d_out, int out_size, void* d_ws, size_t ws_size,
                              hipStream_t stream) {
    const float* inp = (const float*)d_in[0];
    const float* paw = (const float*)d_in[1];
    const float* pab = (const float*)d_in[2];
    const float* pmw = (const float*)d_in[3];
    const float* pmb = (const float*)d_in[4];
    const float* gw  = (const float*)d_in[5];
    const float* gb  = (const float*)d_in[6];
    const float* ow  = (const float*)d_in[7];
    const float* ob  = (const float*)d_in[8];

    float* ws = (float*)d_ws;
    float* xavg = ws;
    float* xmax = ws + 16384;
    float* ypart = ws + OFF_YPART;
    float* out = (float*)d_out;

    kreduce<<<16384, 256, 0, stream>>>(inp, xavg, xmax);
    kprep<<<1024, 512, 0, stream>>>(
        xavg, xmax, ws, paw, pab, pmw, pmb, ow,
        (const float*)d_in[9],  (const float*)d_in[10], (const float*)d_in[11], (const float*)d_in[12],
        (const float*)d_in[13], (const float*)d_in[14], (const float*)d_in[16], (const float*)d_in[17],
        (const float*)d_in[18], (const float*)d_in[19], (const float*)d_in[20], (const float*)d_in[21],
        (const float*)d_in[22], (const float*)d_in[23], (const float*)d_in[25], (const float*)d_in[26]);
    kscan<<<256, 256, 0, stream>>>(
        ws, (const float*)d_in[15], (const float*)d_in[24]);
    kfinal<<<64, 256, 0, stream>>>(xavg, xmax, ypart, gw, gb, ob, out);
}

// Round 21
// 123.597 us; speedup vs baseline: 1.8176x; 1.0789x over previous
//
#include <hip/hip_runtime.h>
#include <math.h>

// ws float-offset layout (ws >= 1 GiB, we use ~56 MB):
// xavg  [0, 16384)
// xmax  [16384, 32768)
// ypart [32768, 294912)                16 slots x 16384: slot = c*4 + dquarter
// PD    [294912, +4194304)             delta^T   [c][b][chunk][d][t]  (64x64 tiles)
// PX    PD+4194304                     delta*xi^T
// PG    PX+4194304                     g^T  (silu(z)*wfold)
// BCB   PG+4194304 (+524288)           B [c][b][chunk][s][t]
// BCC   BCB+524288                     C [c][b][chunk][s][t]
// YB    BCC+524288 (+65536)            ybase [c][b][t]
#define OFF_YPART 32768
#define OFF_PD    294912
#define OFF_PX    (OFF_PD + 4194304)
#define OFF_PG    (OFF_PX + 4194304)
#define OFF_BCB   (OFF_PG + 4194304)
#define OFF_BCC   (OFF_BCB + 524288)
#define OFF_YB    (OFF_BCC + 524288)

__global__ __launch_bounds__(256) void kreduce(const float* __restrict__ in,
                                               float* __restrict__ xavg,
                                               float* __restrict__ xmax) {
    const int bl = blockIdx.x;            // 0..16383  (= b*512 + l)
    const float* p = in + (size_t)bl * 4096;
    const int t = threadIdx.x;
    float s = 0.f, m = -INFINITY;
#pragma unroll
    for (int it = 0; it < 4; ++it) {
        float4 v = *reinterpret_cast<const float4*>(p + (size_t)(it * 256 + t) * 4);
        s += v.x + v.y + v.z + v.w;
        m = fmaxf(m, fmaxf(fmaxf(v.x, v.y), fmaxf(v.z, v.w)));
    }
#pragma unroll
    for (int o = 1; o < 64; o <<= 1) {
        s += __shfl_xor(s, o);
        m = fmaxf(m, __shfl_xor(m, o));
    }
    __shared__ float ls[4], lm[4];
    const int w = t >> 6;
    if ((t & 63) == 0) { ls[w] = s; lm[w] = m; }
    __syncthreads();
    if (t == 0) {
        s = ls[0] + ls[1] + ls[2] + ls[3];
        m = fmaxf(fmaxf(lm[0], lm[1]), fmaxf(lm[2], lm[3]));
        xavg[bl] = s * (1.f / 4096.f);
        xmax[bl] = m;
    }
}

// slot of dbc j-index (j: 0,1=dt; 2..17=B; 18..33=C) in interleaved record
__device__ __forceinline__ int dbc_slot(int j) {
    return j < 2 ? j : (j < 18 ? 2 * j - 2 : 2 * j - 33);
}

// kprep: A-phases + full A3 precompute. (r11/r18 form — session optimum)
__global__ __launch_bounds__(512) void kprep(
    const float* __restrict__ xavg, const float* __restrict__ xmax,
    float* __restrict__ ws,
    const float* __restrict__ paw, const float* __restrict__ pab,
    const float* __restrict__ pmw, const float* __restrict__ pmb,
    const float* __restrict__ outw_outer,
    const float* __restrict__ f_in_w, const float* __restrict__ f_conv_w,
    const float* __restrict__ f_conv_b, const float* __restrict__ f_xproj_w,
    const float* __restrict__ f_dt_w, const float* __restrict__ f_dt_b,
    const float* __restrict__ f_D, const float* __restrict__ f_out_w,
    const float* __restrict__ b_in_w, const float* __restrict__ b_conv_w,
    const float* __restrict__ b_conv_b, const float* __restrict__ b_xproj_w,
    const float* __restrict__ b_dt_w, const float* __restrict__ b_dt_b,
    const float* __restrict__ b_D, const float* __restrict__ b_out_w)
{
    const int tid = threadIdx.x;
    const int c  = blockIdx.x >> 8;
    const int b  = (blockIdx.x >> 3) & 31;
    const int cq = blockIdx.x & 7;
    const int strm = c >> 1, dir = c & 1;

    const float* in_w = dir ? b_in_w   : f_in_w;
    const float* cwp  = dir ? b_conv_w : f_conv_w;
    const float* cbp  = dir ? b_conv_b : f_conv_b;
    const float* xpw  = dir ? b_xproj_w: f_xproj_w;
    const float* dtwp = dir ? b_dt_w   : f_dt_w;
    const float* dtbp = dir ? b_dt_b   : f_dt_b;
    const float* Dpar = dir ? b_D      : f_D;
    const float* owp  = dir ? b_out_w  : f_out_w;
    const float* projw = strm ? pmw : paw;
    const float* projb = strm ? pmb : pab;
    const float* xin   = strm ? xmax : xavg;

    __shared__ float sseq4[68];
    __shared__ float su[128], sv[128];
    __shared__ float scw[64][4], scb[64], sdtw[64][2], sdtb[64], sD[64], swf[64];
    __shared__ float sxp[34][68];
    __shared__ float sxi[64][68];
    __shared__ float sdbc[64][37];

    if (tid < 67) {
        int g = cq * 64 - 3 + tid;
        float val = 0.f;
        if (g >= 0) val = xin[b * 512 + (dir ? (511 - g) : g)];
        sseq4[tid] = val;
    }
    if (tid < 128) {
        float u = 0.f, v = 0.f;
        const float* row = in_w + tid * 32;
#pragma unroll
        for (int m = 0; m < 32; ++m) {
            u = fmaf(row[m], projw[m], u);
            v = fmaf(row[m], projb[m], v);
        }
        su[tid] = u; sv[tid] = v;
    }
    if (tid < 64) {
#pragma unroll
        for (int k = 0; k < 4; ++k) scw[tid][k] = cwp[tid * 4 + k];
        scb[tid] = cbp[tid];
        sdtw[tid][0] = dtwp[tid * 2];
        sdtw[tid][1] = dtwp[tid * 2 + 1];
        sdtb[tid] = dtbp[tid];
        sD[tid] = Dpar[tid];
        float wf = 0.f;
#pragma unroll
        for (int m = 0; m < 32; ++m) wf = fmaf(outw_outer[m], owp[m * 64 + tid], wf);
        swf[tid] = wf;
    }
    for (int i = tid; i < 34 * 64; i += 512) sxp[i >> 6][i & 63] = xpw[i];
    __syncthreads();

    const int ll8 = tid >> 3;
    const int j8  = tid & 7;
    const int gi  = cq * 64 + ll8;

    // A1: xi for all 64 d
    {
        float t0 = sseq4[ll8], t1 = sseq4[ll8 + 1], t2 = sseq4[ll8 + 2], t3 = sseq4[ll8 + 3];
        float vv0 = (gi >= 3) ? 1.f : 0.f;
        float vv1 = (gi >= 2) ? 1.f : 0.f;
        float vv2 = (gi >= 1) ? 1.f : 0.f;
#pragma unroll
        for (int k = 0; k < 8; ++k) {
            int di = j8 * 8 + k;
            float u = su[di], v = sv[di];
            float xc = scw[di][0] * fmaf(t0, u, vv0 * v)
                     + scw[di][1] * fmaf(t1, u, vv1 * v)
                     + scw[di][2] * fmaf(t2, u, vv2 * v)
                     + scw[di][3] * fmaf(t3, u, v);
            xc += scb[di];
            float sig = 1.f / (1.f + __expf(-xc));
            sxi[ll8][di] = xc * sig;
        }
    }
    __syncthreads();

    // A2: dbc = xi @ xproj_w.T (unroll 2: spill discipline, r2-r9 lesson)
    {
        float a0 = 0.f, a1 = 0.f, a2 = 0.f, a3 = 0.f, a4 = 0.f;
        const float4* xr4 = reinterpret_cast<const float4*>(&sxi[ll8][0]);
        const float4* r0 = reinterpret_cast<const float4*>(&sxp[j8 + 0][0]);
        const float4* r1 = reinterpret_cast<const float4*>(&sxp[j8 + 8][0]);
        const float4* r2 = reinterpret_cast<const float4*>(&sxp[j8 + 16][0]);
        const float4* r3 = reinterpret_cast<const float4*>(&sxp[j8 + 24][0]);
        const float4* r4 = (j8 < 2) ? reinterpret_cast<const float4*>(&sxp[j8 + 32][0]) : r0;
        bool extra = (j8 < 2);
#pragma unroll 2
        for (int q = 0; q < 16; ++q) {
            float4 x = xr4[q];
            float4 w;
            w = r0[q]; a0 = fmaf(x.x,w.x,fmaf(x.y,w.y,fmaf(x.z,w.z,fmaf(x.w,w.w,a0))));
            w = r1[q]; a1 = fmaf(x.x,w.x,fmaf(x.y,w.y,fmaf(x.z,w.z,fmaf(x.w,w.w,a1))));
            w = r2[q]; a2 = fmaf(x.x,w.x,fmaf(x.y,w.y,fmaf(x.z,w.z,fmaf(x.w,w.w,a2))));
            w = r3[q]; a3 = fmaf(x.x,w.x,fmaf(x.y,w.y,fmaf(x.z,w.z,fmaf(x.w,w.w,a3))));
            if (extra) { w = r4[q]; a4 = fmaf(x.x,w.x,fmaf(x.y,w.y,fmaf(x.z,w.z,fmaf(x.w,w.w,a4)))); }
        }
        sdbc[ll8][dbc_slot(j8)]      = a0;
        sdbc[ll8][dbc_slot(j8 + 8)]  = a1;
        sdbc[ll8][dbc_slot(j8 + 16)] = a2;
        sdbc[ll8][dbc_slot(j8 + 24)] = a3;
        if (extra) sdbc[ll8][dbc_slot(j8 + 32)] = a4;
    }
    __syncthreads();

    // A3: delta (softplus), delta*xi, g, ybase -> global transposed
    {
        const size_t tile = ((size_t)(c * 32 + b) * 8 + cq) * 4096;
        float dt0 = sdbc[ll8][0], dt1 = sdbc[ll8][1];
        float x3 = sseq4[ll8 + 3];
        float ybp = 0.f;
#pragma unroll 2
        for (int k = 0; k < 8; ++k) {
            int di = j8 * 8 + k;
            float xi = sxi[ll8][di];
            float pre = fmaf(dt0, sdtw[di][0], fmaf(dt1, sdtw[di][1], sdtb[di]));
            float sp = (pre > 20.f) ? pre : __logf(1.f + __expf(pre));
            float zv = fmaf(x3, su[64 + di], sv[64 + di]);
            float g = (zv / (1.f + __expf(-zv))) * swf[di];
            ws[OFF_PD + tile + di * 64 + ll8] = sp;
            ws[OFF_PX + tile + di * 64 + ll8] = sp * xi;
            ws[OFF_PG + tile + di * 64 + ll8] = g;
            ybp = fmaf(g * sD[di], xi, ybp);
        }
        ybp += __shfl_xor(ybp, 1);
        ybp += __shfl_xor(ybp, 2);
        ybp += __shfl_xor(ybp, 4);
        if (j8 == 0) ws[OFF_YB + (size_t)(c * 32 + b) * 512 + gi] = ybp;
    }

    // B/C copy -> [s][t] layout (coalesced over t)
    {
        const size_t bb = ((size_t)(c * 32 + b) * 8 + cq) * 1024;
        for (int i = tid; i < 1024; i += 512) {
            int s = i >> 6, t = i & 63;
            ws[OFF_BCB + bb + i] = sdbc[t][2 + 2 * s];
            ws[OFF_BCC + bb + i] = sdbc[t][3 + 2 * s];
        }
    }
}

// DPP add over 16-lane rows: after shl 1,2,4,8, lane (s==0) holds the row sum.
#define DPP_ADD(v, ctrl) ((v) + __int_as_float(__builtin_amdgcn_update_dpp(0, __float_as_int(v), (ctrl), 0xF, 0xF, true)))

// kscan: pure scan. One block per (c, dquarter, b): 512 blocks x 256 threads.
// r21 change (T14 async-STAGE): prefetch chunk+1's rows into REGISTERS before
// the scan of the current chunk (HBM/L3 latency hides under ~1700 cyc of scan
// VALU), ds_write after the fold barrier. Same barrier count. r19 diagnostic:
// kscan = 49us vs ~11us issue-bound -> exposed staging latency is the gap.
__global__ __launch_bounds__(256) void kscan(
    float* __restrict__ ws,
    const float* __restrict__ f_A_log, const float* __restrict__ b_A_log)
{
    const int tid = threadIdx.x;
    const int c  = blockIdx.x >> 7;
    const int dq = (blockIdx.x >> 5) & 3;
    const int b  = blockIdx.x & 31;
    const int dir = c & 1;
    const float* alog = dir ? b_A_log : f_A_log;

    const int dd = tid >> 4;
    const int s  = tid & 15;
    const int d  = dq * 16 + dd;
    const float cA = -expf(alog[d * 16 + s]) * 1.44269504088896340736f;
    float h = 0.f;

    __shared__ float sd[16][68], sx[16][68], sg[16][68];
    __shared__ float sB[16][68], sC[16][68];
    __shared__ float syT[16][68];
    __shared__ float syb[64];

    const int srow = tid >> 4;
    const int scol = (tid & 15) * 4;
    float* ypart = ws + OFF_YPART;
    const size_t cb512 = (size_t)(c * 32 + b) * 512;

    // initial stage: chunk 0
    {
        const size_t tb = (size_t)(c * 32 + b) * 8;
        *reinterpret_cast<float4*>(&sd[srow][scol]) =
            *reinterpret_cast<const float4*>(ws + OFF_PD + tb * 4096 + dq * 1024 + srow * 64 + scol);
        *reinterpret_cast<float4*>(&sx[srow][scol]) =
            *reinterpret_cast<const float4*>(ws + OFF_PX + tb * 4096 + dq * 1024 + srow * 64 + scol);
        *reinterpret_cast<float4*>(&sg[srow][scol]) =
            *reinterpret_cast<const float4*>(ws + OFF_PG + tb * 4096 + dq * 1024 + srow * 64 + scol);
        *reinterpret_cast<float4*>(&sB[srow][scol]) =
            *reinterpret_cast<const float4*>(ws + OFF_BCB + tb * 1024 + srow * 64 + scol);
        *reinterpret_cast<float4*>(&sC[srow][scol]) =
            *reinterpret_cast<const float4*>(ws + OFF_BCC + tb * 1024 + srow * 64 + scol);
        if (dq == 0 && tid < 64) syb[tid] = ws[OFF_YB + cb512 + tid];
    }
    __syncthreads();

    for (int chunk = 0; chunk < 8; ++chunk) {
        // T14: issue next-chunk prefetch loads to registers (latency hides
        // under the scan compute below).
        float4 nd, nx, ng, nB, nC;
        float nyb = 0.f;
        const bool pf = (chunk < 7);
        if (pf) {
            const size_t tb1 = (size_t)(c * 32 + b) * 8 + chunk + 1;
            nd = *reinterpret_cast<const float4*>(ws + OFF_PD + tb1 * 4096 + dq * 1024 + srow * 64 + scol);
            nx = *reinterpret_cast<const float4*>(ws + OFF_PX + tb1 * 4096 + dq * 1024 + srow * 64 + scol);
            ng = *reinterpret_cast<const float4*>(ws + OFF_PG + tb1 * 4096 + dq * 1024 + srow * 64 + scol);
            nB = *reinterpret_cast<const float4*>(ws + OFF_BCB + tb1 * 1024 + srow * 64 + scol);
            nC = *reinterpret_cast<const float4*>(ws + OFF_BCC + tb1 * 1024 + srow * 64 + scol);
            if (dq == 0 && tid < 64) nyb = ws[OFF_YB + cb512 + (chunk + 1) * 64 + tid];
        }

        // scan 16 m-iters x 4 steps; h carried across chunks
        {
#pragma unroll 2
            for (int m = 0; m < 16; ++m) {
                float4 de = *reinterpret_cast<const float4*>(&sd[dd][4 * m]);
                float4 dx = *reinterpret_cast<const float4*>(&sx[dd][4 * m]);
                float4 gq = *reinterpret_cast<const float4*>(&sg[dd][4 * m]);
                float4 Bq = *reinterpret_cast<const float4*>(&sB[s][4 * m]);
                float4 Cq = *reinterpret_cast<const float4*>(&sC[s][4 * m]);
                float4 val;
                float a, pc;
                a = exp2f(de.x * cA); h = fmaf(a, h, dx.x * Bq.x); pc = h * Cq.x;
                pc = DPP_ADD(pc, 0x101); pc = DPP_ADD(pc, 0x102);
                pc = DPP_ADD(pc, 0x104); pc = DPP_ADD(pc, 0x108);
                val.x = pc * gq.x;
                a = exp2f(de.y * cA); h = fmaf(a, h, dx.y * Bq.y); pc = h * Cq.y;
                pc = DPP_ADD(pc, 0x101); pc = DPP_ADD(pc, 0x102);
                pc = DPP_ADD(pc, 0x104); pc = DPP_ADD(pc, 0x108);
                val.y = pc * gq.y;
                a = exp2f(de.z * cA); h = fmaf(a, h, dx.z * Bq.z); pc = h * Cq.z;
                pc = DPP_ADD(pc, 0x101); pc = DPP_ADD(pc, 0x102);
                pc = DPP_ADD(pc, 0x104); pc = DPP_ADD(pc, 0x108);
                val.z = pc * gq.z;
                a = exp2f(de.w * cA); h = fmaf(a, h, dx.w * Bq.w); pc = h * Cq.w;
                pc = DPP_ADD(pc, 0x101); pc = DPP_ADD(pc, 0x102);
                pc = DPP_ADD(pc, 0x104); pc = DPP_ADD(pc, 0x108);
                val.w = pc * gq.w;
                if (s == 0) *reinterpret_cast<float4*>(&syT[dd][4 * m]) = val;
            }
        }
        __syncthreads();

        // fold over 16 dd -> scalar partial into slot (c*4 + dq)
        {
            const int tt4 = tid >> 2;
            const int j4  = tid & 3;
            float acc = syT[j4 * 4][tt4] + syT[j4 * 4 + 1][tt4]
                      + syT[j4 * 4 + 2][tt4] + syT[j4 * 4 + 3][tt4];
            acc += __shfl_xor(acc, 1);
            acc += __shfl_xor(acc, 2);
            if (j4 == 0) {
                int i = chunk * 64 + tt4;
                int l = dir ? (511 - i) : i;
                float res = acc + (dq == 0 ? syb[tt4] : 0.f);
                ypart[((c * 4 + dq) * 32 + b) * 512 + l] = res;
            }
        }
        __syncthreads();

        // write prefetched chunk to LDS (all reads of old chunk complete)
        if (pf) {
            *reinterpret_cast<float4*>(&sd[srow][scol]) = nd;
            *reinterpret_cast<float4*>(&sx[srow][scol]) = nx;
            *reinterpret_cast<float4*>(&sg[srow][scol]) = ng;
            *reinterpret_cast<float4*>(&sB[srow][scol]) = nB;
            *reinterpret_cast<float4*>(&sC[srow][scol]) = nC;
            if (dq == 0 && tid < 64) syb[tid] = nyb;
            __syncthreads();
        }
    }
}

__global__ __launch_bounds__(256) void kfinal(const float* __restrict__ xavg,
                                              const float* __restrict__ xmax,
                                              const float* __restrict__ ypart,
                                              const float* __restrict__ gate_w,
                                              const float* __restrict__ gate_b,
                                              const float* __restrict__ out_b,
                                              float* __restrict__ out) {
    const int idx = blockIdx.x * 256 + threadIdx.x;
    float xa = xavg[idx], xm = xmax[idx];
    float alpha = 1.f / (1.f + __expf(-(fmaf(xa, gate_w[0], fmaf(xm, gate_w[1], gate_b[0])))));
    float sa = 0.f, sm = 0.f;
#pragma unroll
    for (int k = 0; k < 8; ++k)  sa += ypart[k * 16384 + idx];
#pragma unroll
    for (int k = 8; k < 16; ++k) sm += ypart[k * 16384 + idx];
    float y = alpha * sa + (1.f - alpha) * sm + out_b[0];
    out[idx] = 1.f / (1.f + __expf(-y));
}

extern "C" void kernel_launch(void* const* d_in, const int* in_sizes, int n_in,
                              void* d_out, int out_size, void* d_ws, size_t ws_size,
                              hipStream_t stream) {
    const float* inp = (const float*)d_in[0];
    const float* paw = (const float*)d_in[1];
    const float* pab = (const float*)d_in[2];
    const float* pmw = (const float*)d_in[3];
    const float* pmb = (const float*)d_in[4];
    const float* gw  = (const float*)d_in[5];
    const float* gb  = (const float*)d_in[6];
    const float* ow  = (const float*)d_in[7];
    const float* ob  = (const float*)d_in[8];

    float* ws = (float*)d_ws;
    float* xavg = ws;
    float* xmax = ws + 16384;
    float* ypart = ws + OFF_YPART;
    float* out = (float*)d_out;

    kreduce<<<16384, 256, 0, stream>>>(inp, xavg, xmax);
    kprep<<<1024, 512, 0, stream>>>(
        xavg, xmax, ws, paw, pab, pmw, pmb, ow,
        (const float*)d_in[9],  (const float*)d_in[10], (const float*)d_in[11], (const float*)d_in[12],
        (const float*)d_in[13], (const float*)d_in[14], (const float*)d_in[16], (const float*)d_in[17],
        (const float*)d_in[18], (const float*)d_in[19], (const float*)d_in[20], (const float*)d_in[21],
        (const float*)d_in[22], (const float*)d_in[23], (const float*)d_in[25], (const float*)d_in[26]);
    kscan<<<512, 256, 0, stream>>>(
        ws, (const float*)d_in[15], (const float*)d_in[24]);
    kfinal<<<64, 256, 0, stream>>>(xavg, xmax, ypart, gw, gb, ob, out);
}

// Round 22
// 117.918 us; speedup vs baseline: 1.9051x; 1.0482x over previous
//
#include <hip/hip_runtime.h>
#include <math.h>

// ws float-offset layout (ws >= 1 GiB, we use ~56 MB):
// xavg  [0, 16384)
// xmax  [16384, 32768)
// ypart [32768, 294912)                16 slots x 16384: slot = c*4 + dquarter
// PD    [294912, +4194304)             delta^T   [c][b][chunk][d][t]  (64x64 tiles)
// PX    PD+4194304                     delta*xi^T
// PG    PX+4194304                     g^T  (silu(z)*wfold)
// BCB   PG+4194304 (+524288)           B [c][b][chunk][s][t]
// BCC   BCB+524288                     C [c][b][chunk][s][t]
// YB    BCC+524288 (+65536)            ybase [c][b][t]
#define OFF_YPART 32768
#define OFF_PD    294912
#define OFF_PX    (OFF_PD + 4194304)
#define OFF_PG    (OFF_PX + 4194304)
#define OFF_BCB   (OFF_PG + 4194304)
#define OFF_BCC   (OFF_BCB + 524288)
#define OFF_YB    (OFF_BCC + 524288)

__global__ __launch_bounds__(256) void kreduce(const float* __restrict__ in,
                                               float* __restrict__ xavg,
                                               float* __restrict__ xmax) {
    const int bl = blockIdx.x;            // 0..16383  (= b*512 + l)
    const float* p = in + (size_t)bl * 4096;
    const int t = threadIdx.x;
    float s = 0.f, m = -INFINITY;
#pragma unroll
    for (int it = 0; it < 4; ++it) {
        float4 v = *reinterpret_cast<const float4*>(p + (size_t)(it * 256 + t) * 4);
        s += v.x + v.y + v.z + v.w;
        m = fmaxf(m, fmaxf(fmaxf(v.x, v.y), fmaxf(v.z, v.w)));
    }
#pragma unroll
    for (int o = 1; o < 64; o <<= 1) {
        s += __shfl_xor(s, o);
        m = fmaxf(m, __shfl_xor(m, o));
    }
    __shared__ float ls[4], lm[4];
    const int w = t >> 6;
    if ((t & 63) == 0) { ls[w] = s; lm[w] = m; }
    __syncthreads();
    if (t == 0) {
        s = ls[0] + ls[1] + ls[2] + ls[3];
        m = fmaxf(fmaxf(lm[0], lm[1]), fmaxf(lm[2], lm[3]));
        xavg[bl] = s * (1.f / 4096.f);
        xmax[bl] = m;
    }
}

// slot of dbc j-index (j: 0,1=dt; 2..17=B; 18..33=C) in interleaved record
__device__ __forceinline__ int dbc_slot(int j) {
    return j < 2 ? j : (j < 18 ? 2 * j - 2 : 2 * j - 33);
}

// kprep: A-phases + full A3 precompute. (r11/r18 form — session optimum)
__global__ __launch_bounds__(512) void kprep(
    const float* __restrict__ xavg, const float* __restrict__ xmax,
    float* __restrict__ ws,
    const float* __restrict__ paw, const float* __restrict__ pab,
    const float* __restrict__ pmw, const float* __restrict__ pmb,
    const float* __restrict__ outw_outer,
    const float* __restrict__ f_in_w, const float* __restrict__ f_conv_w,
    const float* __restrict__ f_conv_b, const float* __restrict__ f_xproj_w,
    const float* __restrict__ f_dt_w, const float* __restrict__ f_dt_b,
    const float* __restrict__ f_D, const float* __restrict__ f_out_w,
    const float* __restrict__ b_in_w, const float* __restrict__ b_conv_w,
    const float* __restrict__ b_conv_b, const float* __restrict__ b_xproj_w,
    const float* __restrict__ b_dt_w, const float* __restrict__ b_dt_b,
    const float* __restrict__ b_D, const float* __restrict__ b_out_w)
{
    const int tid = threadIdx.x;
    const int c  = blockIdx.x >> 8;
    const int b  = (blockIdx.x >> 3) & 31;
    const int cq = blockIdx.x & 7;
    const int strm = c >> 1, dir = c & 1;

    const float* in_w = dir ? b_in_w   : f_in_w;
    const float* cwp  = dir ? b_conv_w : f_conv_w;
    const float* cbp  = dir ? b_conv_b : f_conv_b;
    const float* xpw  = dir ? b_xproj_w: f_xproj_w;
    const float* dtwp = dir ? b_dt_w   : f_dt_w;
    const float* dtbp = dir ? b_dt_b   : f_dt_b;
    const float* Dpar = dir ? b_D      : f_D;
    const float* owp  = dir ? b_out_w  : f_out_w;
    const float* projw = strm ? pmw : paw;
    const float* projb = strm ? pmb : pab;
    const float* xin   = strm ? xmax : xavg;

    __shared__ float sseq4[68];
    __shared__ float su[128], sv[128];
    __shared__ float scw[64][4], scb[64], sdtw[64][2], sdtb[64], sD[64], swf[64];
    __shared__ float sxp[34][68];
    __shared__ float sxi[64][68];
    __shared__ float sdbc[64][37];

    if (tid < 67) {
        int g = cq * 64 - 3 + tid;
        float val = 0.f;
        if (g >= 0) val = xin[b * 512 + (dir ? (511 - g) : g)];
        sseq4[tid] = val;
    }
    if (tid < 128) {
        float u = 0.f, v = 0.f;
        const float* row = in_w + tid * 32;
#pragma unroll
        for (int m = 0; m < 32; ++m) {
            u = fmaf(row[m], projw[m], u);
            v = fmaf(row[m], projb[m], v);
        }
        su[tid] = u; sv[tid] = v;
    }
    if (tid < 64) {
#pragma unroll
        for (int k = 0; k < 4; ++k) scw[tid][k] = cwp[tid * 4 + k];
        scb[tid] = cbp[tid];
        sdtw[tid][0] = dtwp[tid * 2];
        sdtw[tid][1] = dtwp[tid * 2 + 1];
        sdtb[tid] = dtbp[tid];
        sD[tid] = Dpar[tid];
        float wf = 0.f;
#pragma unroll
        for (int m = 0; m < 32; ++m) wf = fmaf(outw_outer[m], owp[m * 64 + tid], wf);
        swf[tid] = wf;
    }
    for (int i = tid; i < 34 * 64; i += 512) sxp[i >> 6][i & 63] = xpw[i];
    __syncthreads();

    const int ll8 = tid >> 3;
    const int j8  = tid & 7;
    const int gi  = cq * 64 + ll8;

    // A1: xi for all 64 d
    {
        float t0 = sseq4[ll8], t1 = sseq4[ll8 + 1], t2 = sseq4[ll8 + 2], t3 = sseq4[ll8 + 3];
        float vv0 = (gi >= 3) ? 1.f : 0.f;
        float vv1 = (gi >= 2) ? 1.f : 0.f;
        float vv2 = (gi >= 1) ? 1.f : 0.f;
#pragma unroll
        for (int k = 0; k < 8; ++k) {
            int di = j8 * 8 + k;
            float u = su[di], v = sv[di];
            float xc = scw[di][0] * fmaf(t0, u, vv0 * v)
                     + scw[di][1] * fmaf(t1, u, vv1 * v)
                     + scw[di][2] * fmaf(t2, u, vv2 * v)
                     + scw[di][3] * fmaf(t3, u, v);
            xc += scb[di];
            float sig = 1.f / (1.f + __expf(-xc));
            sxi[ll8][di] = xc * sig;
        }
    }
    __syncthreads();

    // A2: dbc = xi @ xproj_w.T (unroll 2: spill discipline, r2-r9 lesson)
    {
        float a0 = 0.f, a1 = 0.f, a2 = 0.f, a3 = 0.f, a4 = 0.f;
        const float4* xr4 = reinterpret_cast<const float4*>(&sxi[ll8][0]);
        const float4* r0 = reinterpret_cast<const float4*>(&sxp[j8 + 0][0]);
        const float4* r1 = reinterpret_cast<const float4*>(&sxp[j8 + 8][0]);
        const float4* r2 = reinterpret_cast<const float4*>(&sxp[j8 + 16][0]);
        const float4* r3 = reinterpret_cast<const float4*>(&sxp[j8 + 24][0]);
        const float4* r4 = (j8 < 2) ? reinterpret_cast<const float4*>(&sxp[j8 + 32][0]) : r0;
        bool extra = (j8 < 2);
#pragma unroll 2
        for (int q = 0; q < 16; ++q) {
            float4 x = xr4[q];
            float4 w;
            w = r0[q]; a0 = fmaf(x.x,w.x,fmaf(x.y,w.y,fmaf(x.z,w.z,fmaf(x.w,w.w,a0))));
            w = r1[q]; a1 = fmaf(x.x,w.x,fmaf(x.y,w.y,fmaf(x.z,w.z,fmaf(x.w,w.w,a1))));
            w = r2[q]; a2 = fmaf(x.x,w.x,fmaf(x.y,w.y,fmaf(x.z,w.z,fmaf(x.w,w.w,a2))));
            w = r3[q]; a3 = fmaf(x.x,w.x,fmaf(x.y,w.y,fmaf(x.z,w.z,fmaf(x.w,w.w,a3))));
            if (extra) { w = r4[q]; a4 = fmaf(x.x,w.x,fmaf(x.y,w.y,fmaf(x.z,w.z,fmaf(x.w,w.w,a4)))); }
        }
        sdbc[ll8][dbc_slot(j8)]      = a0;
        sdbc[ll8][dbc_slot(j8 + 8)]  = a1;
        sdbc[ll8][dbc_slot(j8 + 16)] = a2;
        sdbc[ll8][dbc_slot(j8 + 24)] = a3;
        if (extra) sdbc[ll8][dbc_slot(j8 + 32)] = a4;
    }
    __syncthreads();

    // A3: delta (softplus), delta*xi, g, ybase -> global transposed
    {
        const size_t tile = ((size_t)(c * 32 + b) * 8 + cq) * 4096;
        float dt0 = sdbc[ll8][0], dt1 = sdbc[ll8][1];
        float x3 = sseq4[ll8 + 3];
        float ybp = 0.f;
#pragma unroll 2
        for (int k = 0; k < 8; ++k) {
            int di = j8 * 8 + k;
            float xi = sxi[ll8][di];
            float pre = fmaf(dt0, sdtw[di][0], fmaf(dt1, sdtw[di][1], sdtb[di]));
            float sp = (pre > 20.f) ? pre : __logf(1.f + __expf(pre));
            float zv = fmaf(x3, su[64 + di], sv[64 + di]);
            float g = (zv / (1.f + __expf(-zv))) * swf[di];
            ws[OFF_PD + tile + di * 64 + ll8] = sp;
            ws[OFF_PX + tile + di * 64 + ll8] = sp * xi;
            ws[OFF_PG + tile + di * 64 + ll8] = g;
            ybp = fmaf(g * sD[di], xi, ybp);
        }
        ybp += __shfl_xor(ybp, 1);
        ybp += __shfl_xor(ybp, 2);
        ybp += __shfl_xor(ybp, 4);
        if (j8 == 0) ws[OFF_YB + (size_t)(c * 32 + b) * 512 + gi] = ybp;
    }

    // B/C copy -> [s][t] layout (coalesced over t)
    {
        const size_t bb = ((size_t)(c * 32 + b) * 8 + cq) * 1024;
        for (int i = tid; i < 1024; i += 512) {
            int s = i >> 6, t = i & 63;
            ws[OFF_BCB + bb + i] = sdbc[t][2 + 2 * s];
            ws[OFF_BCC + bb + i] = sdbc[t][3 + 2 * s];
        }
    }
}

// DPP add over 16-lane rows (row_shl). After shl 1,2: lane s holds sum of
// p_s..p_{s+3} (zeros past row end via bound_ctrl) -> lanes s%4==0 hold their
// 4-group sums.
#define DPP_ADD(v, ctrl) ((v) + __int_as_float(__builtin_amdgcn_update_dpp(0, __float_as_int(v), (ctrl), 0xF, 0xF, true)))

// kscan: pure scan. One block per (c, dquarter, b): 512 blocks x 256 threads.
// r22 changes: (1) 4-lane DPP reduce (2 DPP_ADDs, was 4) + 4-partial fold;
// (2) double-buffered LDS — register prefetch (r21/T14) lands in the other
// buffer right after the scan, removing the 3rd barrier (2 barriers/chunk).
__global__ __launch_bounds__(256) void kscan(
    float* __restrict__ ws,
    const float* __restrict__ f_A_log, const float* __restrict__ b_A_log)
{
    const int tid = threadIdx.x;
    const int c  = blockIdx.x >> 7;
    const int dq = (blockIdx.x >> 5) & 3;
    const int b  = blockIdx.x & 31;
    const int dir = c & 1;
    const float* alog = dir ? b_A_log : f_A_log;

    const int dd = tid >> 4;
    const int s  = tid & 15;
    const int d  = dq * 16 + dd;
    const float cA = -expf(alog[d * 16 + s]) * 1.44269504088896340736f;
    float h = 0.f;

    __shared__ float sd[2][16][68], sx[2][16][68], sg[2][16][68];
    __shared__ float sB[2][16][68], sC[2][16][68];
    __shared__ float syT[4][17][68];   // 4 s-group partials; pad 17 -> stride 1156 % 32 = 4 (conflict-free)
    __shared__ float syb[2][64];

    const int srow = tid >> 4;
    const int scol = (tid & 15) * 4;
    float* ypart = ws + OFF_YPART;
    const size_t cb512 = (size_t)(c * 32 + b) * 512;

    // initial stage: chunk 0 -> buffer 0
    {
        const size_t tb = (size_t)(c * 32 + b) * 8;
        *reinterpret_cast<float4*>(&sd[0][srow][scol]) =
            *reinterpret_cast<const float4*>(ws + OFF_PD + tb * 4096 + dq * 1024 + srow * 64 + scol);
        *reinterpret_cast<float4*>(&sx[0][srow][scol]) =
            *reinterpret_cast<const float4*>(ws + OFF_PX + tb * 4096 + dq * 1024 + srow * 64 + scol);
        *reinterpret_cast<float4*>(&sg[0][srow][scol]) =
            *reinterpret_cast<const float4*>(ws + OFF_PG + tb * 4096 + dq * 1024 + srow * 64 + scol);
        *reinterpret_cast<float4*>(&sB[0][srow][scol]) =
            *reinterpret_cast<const float4*>(ws + OFF_BCB + tb * 1024 + srow * 64 + scol);
        *reinterpret_cast<float4*>(&sC[0][srow][scol]) =
            *reinterpret_cast<const float4*>(ws + OFF_BCC + tb * 1024 + srow * 64 + scol);
        if (dq == 0 && tid < 64) syb[0][tid] = ws[OFF_YB + cb512 + tid];
    }
    __syncthreads();

    for (int chunk = 0; chunk < 8; ++chunk) {
        const int cur = chunk & 1;
        // T14: issue next-chunk prefetch loads to registers (latency hides
        // under the scan compute below).
        float4 nd, nx, ng, nB, nC;
        float nyb = 0.f;
        const bool pf = (chunk < 7);
        if (pf) {
            const size_t tb1 = (size_t)(c * 32 + b) * 8 + chunk + 1;
            nd = *reinterpret_cast<const float4*>(ws + OFF_PD + tb1 * 4096 + dq * 1024 + srow * 64 + scol);
            nx = *reinterpret_cast<const float4*>(ws + OFF_PX + tb1 * 4096 + dq * 1024 + srow * 64 + scol);
            ng = *reinterpret_cast<const float4*>(ws + OFF_PG + tb1 * 4096 + dq * 1024 + srow * 64 + scol);
            nB = *reinterpret_cast<const float4*>(ws + OFF_BCB + tb1 * 1024 + srow * 64 + scol);
            nC = *reinterpret_cast<const float4*>(ws + OFF_BCC + tb1 * 1024 + srow * 64 + scol);
            if (dq == 0 && tid < 64) nyb = ws[OFF_YB + cb512 + (chunk + 1) * 64 + tid];
        }

        // scan 16 m-iters x 4 steps; h carried across chunks.
        // Per step: 4-lane reduce only; lanes s%4==0 write their group partial.
        {
#pragma unroll 2
            for (int m = 0; m < 16; ++m) {
                float4 de = *reinterpret_cast<const float4*>(&sd[cur][dd][4 * m]);
                float4 dx = *reinterpret_cast<const float4*>(&sx[cur][dd][4 * m]);
                float4 gq = *reinterpret_cast<const float4*>(&sg[cur][dd][4 * m]);
                float4 Bq = *reinterpret_cast<const float4*>(&sB[cur][s][4 * m]);
                float4 Cq = *reinterpret_cast<const float4*>(&sC[cur][s][4 * m]);
                float4 val;
                float a, pc;
                a = exp2f(de.x * cA); h = fmaf(a, h, dx.x * Bq.x); pc = h * Cq.x;
                pc = DPP_ADD(pc, 0x101); pc = DPP_ADD(pc, 0x102);
                val.x = pc * gq.x;
                a = exp2f(de.y * cA); h = fmaf(a, h, dx.y * Bq.y); pc = h * Cq.y;
                pc = DPP_ADD(pc, 0x101); pc = DPP_ADD(pc, 0x102);
                val.y = pc * gq.y;
                a = exp2f(de.z * cA); h = fmaf(a, h, dx.z * Bq.z); pc = h * Cq.z;
                pc = DPP_ADD(pc, 0x101); pc = DPP_ADD(pc, 0x102);
                val.z = pc * gq.z;
                a = exp2f(de.w * cA); h = fmaf(a, h, dx.w * Bq.w); pc = h * Cq.w;
                pc = DPP_ADD(pc, 0x101); pc = DPP_ADD(pc, 0x102);
                val.w = pc * gq.w;
                if ((s & 3) == 0) *reinterpret_cast<float4*>(&syT[s >> 2][dd][4 * m]) = val;
            }
        }

        // write prefetched chunk into the OTHER buffer (no barrier needed:
        // nobody reads buf[cur^1] until after the next barrier)
        if (pf) {
            *reinterpret_cast<float4*>(&sd[cur ^ 1][srow][scol]) = nd;
            *reinterpret_cast<float4*>(&sx[cur ^ 1][srow][scol]) = nx;
            *reinterpret_cast<float4*>(&sg[cur ^ 1][srow][scol]) = ng;
            *reinterpret_cast<float4*>(&sB[cur ^ 1][srow][scol]) = nB;
            *reinterpret_cast<float4*>(&sC[cur ^ 1][srow][scol]) = nC;
            if (dq == 0 && tid < 64) syb[cur ^ 1][tid] = nyb;
        }
        __syncthreads();

        // fold: sum 4 partial-groups x 4 dd per j4-lane -> scalar per t
        {
            const int tt4 = tid >> 2;   // 0..63
            const int j4  = tid & 3;
            float acc = 0.f;
#pragma unroll
            for (int sg4 = 0; sg4 < 4; ++sg4) {
#pragma unroll
                for (int k = 0; k < 4; ++k) {
                    acc += syT[sg4][j4 * 4 + k][tt4];
                }
            }
            acc += __shfl_xor(acc, 1);
            acc += __shfl_xor(acc, 2);
            if (j4 == 0) {
                int i = chunk * 64 + tt4;
                int l = dir ? (511 - i) : i;
                float res = acc + (dq == 0 ? syb[cur][tt4] : 0.f);
                ypart[((c * 4 + dq) * 32 + b) * 512 + l] = res;
            }
        }
        __syncthreads();
    }
}

__global__ __launch_bounds__(256) void kfinal(const float* __restrict__ xavg,
                                              const float* __restrict__ xmax,
                                              const float* __restrict__ ypart,
                                              const float* __restrict__ gate_w,
                                              const float* __restrict__ gate_b,
                                              const float* __restrict__ out_b,
                                              float* __restrict__ out) {
    const int idx = blockIdx.x * 256 + threadIdx.x;
    float xa = xavg[idx], xm = xmax[idx];
    float alpha = 1.f / (1.f + __expf(-(fmaf(xa, gate_w[0], fmaf(xm, gate_w[1], gate_b[0])))));
    float sa = 0.f, sm = 0.f;
#pragma unroll
    for (int k = 0; k < 8; ++k)  sa += ypart[k * 16384 + idx];
#pragma unroll
    for (int k = 8; k < 16; ++k) sm += ypart[k * 16384 + idx];
    float y = alpha * sa + (1.f - alpha) * sm + out_b[0];
    out[idx] = 1.f / (1.f + __expf(-y));
}

extern "C" void kernel_launch(void* const* d_in, const int* in_sizes, int n_in,
                              void* d_out, int out_size, void* d_ws, size_t ws_size,
                              hipStream_t stream) {
    const float* inp = (const float*)d_in[0];
    const float* paw = (const float*)d_in[1];
    const float* pab = (const float*)d_in[2];
    const float* pmw = (const float*)d_in[3];
    const float* pmb = (const float*)d_in[4];
    const float* gw  = (const float*)d_in[5];
    const float* gb  = (const float*)d_in[6];
    const float* ow  = (const float*)d_in[7];
    const float* ob  = (const float*)d_in[8];

    float* ws = (float*)d_ws;
    float* xavg = ws;
    float* xmax = ws + 16384;
    float* ypart = ws + OFF_YPART;
    float* out = (float*)d_out;

    kreduce<<<16384, 256, 0, stream>>>(inp, xavg, xmax);
    kprep<<<1024, 512, 0, stream>>>(
        xavg, xmax, ws, paw, pab, pmw, pmb, ow,
        (const float*)d_in[9],  (const float*)d_in[10], (const float*)d_in[11], (const float*)d_in[12],
        (const float*)d_in[13], (const float*)d_in[14], (const float*)d_in[16], (const float*)d_in[17],
        (const float*)d_in[18], (const float*)d_in[19], (const float*)d_in[20], (const float*)d_in[21],
        (const float*)d_in[22], (const float*)d_in[23], (const float*)d_in[25], (const float*)d_in[26]);
    kscan<<<512, 256, 0, stream>>>(
        ws, (const float*)d_in[15], (const float*)d_in[24]);
    kfinal<<<64, 256, 0, stream>>>(xavg, xmax, ypart, gw, gb, ob, out);
}

// Round 23
// 116.003 us; speedup vs baseline: 1.9366x; 1.0165x over previous
//
#include <hip/hip_runtime.h>
#include <math.h>

// ws float-offset layout (ws >= 1 GiB, we use ~56 MB):
// xavg  [0, 16384)
// xmax  [16384, 32768)
// ypart [32768, 294912)                16 slots x 16384: slot = c*4 + dquarter
// PD    [294912, +4194304)             delta^T   [c][b][chunk][d][t]  (64x64 tiles)
// PX    PD+4194304                     delta*xi^T
// PG    PX+4194304                     g^T  (silu(z)*wfold)
// BCB   PG+4194304 (+524288)           B [c][b][chunk][s][t]
// BCC   BCB+524288                     C [c][b][chunk][s][t]
// YB    BCC+524288 (+65536)            ybase [c][b][t]
#define OFF_YPART 32768
#define OFF_PD    294912
#define OFF_PX    (OFF_PD + 4194304)
#define OFF_PG    (OFF_PX + 4194304)
#define OFF_BCB   (OFF_PG + 4194304)
#define OFF_BCC   (OFF_BCB + 524288)
#define OFF_YB    (OFF_BCC + 524288)

__global__ __launch_bounds__(256) void kreduce(const float* __restrict__ in,
                                               float* __restrict__ xavg,
                                               float* __restrict__ xmax) {
    const int bl = blockIdx.x;            // 0..16383  (= b*512 + l)
    const float* p = in + (size_t)bl * 4096;
    const int t = threadIdx.x;
    float s = 0.f, m = -INFINITY;
#pragma unroll
    for (int it = 0; it < 4; ++it) {
        float4 v = *reinterpret_cast<const float4*>(p + (size_t)(it * 256 + t) * 4);
        s += v.x + v.y + v.z + v.w;
        m = fmaxf(m, fmaxf(fmaxf(v.x, v.y), fmaxf(v.z, v.w)));
    }
#pragma unroll
    for (int o = 1; o < 64; o <<= 1) {
        s += __shfl_xor(s, o);
        m = fmaxf(m, __shfl_xor(m, o));
    }
    __shared__ float ls[4], lm[4];
    const int w = t >> 6;
    if ((t & 63) == 0) { ls[w] = s; lm[w] = m; }
    __syncthreads();
    if (t == 0) {
        s = ls[0] + ls[1] + ls[2] + ls[3];
        m = fmaxf(fmaxf(lm[0], lm[1]), fmaxf(lm[2], lm[3]));
        xavg[bl] = s * (1.f / 4096.f);
        xmax[bl] = m;
    }
}

// slot of dbc j-index (j: 0,1=dt; 2..17=B; 18..33=C) in interleaved record
__device__ __forceinline__ int dbc_slot(int j) {
    return j < 2 ? j : (j < 18 ? 2 * j - 2 : 2 * j - 33);
}

// kprep: A-phases + full A3 precompute. (r11/r18 form — session optimum)
__global__ __launch_bounds__(512) void kprep(
    const float* __restrict__ xavg, const float* __restrict__ xmax,
    float* __restrict__ ws,
    const float* __restrict__ paw, const float* __restrict__ pab,
    const float* __restrict__ pmw, const float* __restrict__ pmb,
    const float* __restrict__ outw_outer,
    const float* __restrict__ f_in_w, const float* __restrict__ f_conv_w,
    const float* __restrict__ f_conv_b, const float* __restrict__ f_xproj_w,
    const float* __restrict__ f_dt_w, const float* __restrict__ f_dt_b,
    const float* __restrict__ f_D, const float* __restrict__ f_out_w,
    const float* __restrict__ b_in_w, const float* __restrict__ b_conv_w,
    const float* __restrict__ b_conv_b, const float* __restrict__ b_xproj_w,
    const float* __restrict__ b_dt_w, const float* __restrict__ b_dt_b,
    const float* __restrict__ b_D, const float* __restrict__ b_out_w)
{
    const int tid = threadIdx.x;
    const int c  = blockIdx.x >> 8;
    const int b  = (blockIdx.x >> 3) & 31;
    const int cq = blockIdx.x & 7;
    const int strm = c >> 1, dir = c & 1;

    const float* in_w = dir ? b_in_w   : f_in_w;
    const float* cwp  = dir ? b_conv_w : f_conv_w;
    const float* cbp  = dir ? b_conv_b : f_conv_b;
    const float* xpw  = dir ? b_xproj_w: f_xproj_w;
    const float* dtwp = dir ? b_dt_w   : f_dt_w;
    const float* dtbp = dir ? b_dt_b   : f_dt_b;
    const float* Dpar = dir ? b_D      : f_D;
    const float* owp  = dir ? b_out_w  : f_out_w;
    const float* projw = strm ? pmw : paw;
    const float* projb = strm ? pmb : pab;
    const float* xin   = strm ? xmax : xavg;

    __shared__ float sseq4[68];
    __shared__ float su[128], sv[128];
    __shared__ float scw[64][4], scb[64], sdtw[64][2], sdtb[64], sD[64], swf[64];
    __shared__ float sxp[34][68];
    __shared__ float sxi[64][68];
    __shared__ float sdbc[64][37];

    if (tid < 67) {
        int g = cq * 64 - 3 + tid;
        float val = 0.f;
        if (g >= 0) val = xin[b * 512 + (dir ? (511 - g) : g)];
        sseq4[tid] = val;
    }
    if (tid < 128) {
        float u = 0.f, v = 0.f;
        const float* row = in_w + tid * 32;
#pragma unroll
        for (int m = 0; m < 32; ++m) {
            u = fmaf(row[m], projw[m], u);
            v = fmaf(row[m], projb[m], v);
        }
        su[tid] = u; sv[tid] = v;
    }
    if (tid < 64) {
#pragma unroll
        for (int k = 0; k < 4; ++k) scw[tid][k] = cwp[tid * 4 + k];
        scb[tid] = cbp[tid];
        sdtw[tid][0] = dtwp[tid * 2];
        sdtw[tid][1] = dtwp[tid * 2 + 1];
        sdtb[tid] = dtbp[tid];
        sD[tid] = Dpar[tid];
        float wf = 0.f;
#pragma unroll
        for (int m = 0; m < 32; ++m) wf = fmaf(outw_outer[m], owp[m * 64 + tid], wf);
        swf[tid] = wf;
    }
    for (int i = tid; i < 34 * 64; i += 512) sxp[i >> 6][i & 63] = xpw[i];
    __syncthreads();

    const int ll8 = tid >> 3;
    const int j8  = tid & 7;
    const int gi  = cq * 64 + ll8;

    // A1: xi for all 64 d
    {
        float t0 = sseq4[ll8], t1 = sseq4[ll8 + 1], t2 = sseq4[ll8 + 2], t3 = sseq4[ll8 + 3];
        float vv0 = (gi >= 3) ? 1.f : 0.f;
        float vv1 = (gi >= 2) ? 1.f : 0.f;
        float vv2 = (gi >= 1) ? 1.f : 0.f;
#pragma unroll
        for (int k = 0; k < 8; ++k) {
            int di = j8 * 8 + k;
            float u = su[di], v = sv[di];
            float xc = scw[di][0] * fmaf(t0, u, vv0 * v)
                     + scw[di][1] * fmaf(t1, u, vv1 * v)
                     + scw[di][2] * fmaf(t2, u, vv2 * v)
                     + scw[di][3] * fmaf(t3, u, v);
            xc += scb[di];
            float sig = 1.f / (1.f + __expf(-xc));
            sxi[ll8][di] = xc * sig;
        }
    }
    __syncthreads();

    // A2: dbc = xi @ xproj_w.T (unroll 2: spill discipline, r2-r9 lesson)
    {
        float a0 = 0.f, a1 = 0.f, a2 = 0.f, a3 = 0.f, a4 = 0.f;
        const float4* xr4 = reinterpret_cast<const float4*>(&sxi[ll8][0]);
        const float4* r0 = reinterpret_cast<const float4*>(&sxp[j8 + 0][0]);
        const float4* r1 = reinterpret_cast<const float4*>(&sxp[j8 + 8][0]);
        const float4* r2 = reinterpret_cast<const float4*>(&sxp[j8 + 16][0]);
        const float4* r3 = reinterpret_cast<const float4*>(&sxp[j8 + 24][0]);
        const float4* r4 = (j8 < 2) ? reinterpret_cast<const float4*>(&sxp[j8 + 32][0]) : r0;
        bool extra = (j8 < 2);
#pragma unroll 2
        for (int q = 0; q < 16; ++q) {
            float4 x = xr4[q];
            float4 w;
            w = r0[q]; a0 = fmaf(x.x,w.x,fmaf(x.y,w.y,fmaf(x.z,w.z,fmaf(x.w,w.w,a0))));
            w = r1[q]; a1 = fmaf(x.x,w.x,fmaf(x.y,w.y,fmaf(x.z,w.z,fmaf(x.w,w.w,a1))));
            w = r2[q]; a2 = fmaf(x.x,w.x,fmaf(x.y,w.y,fmaf(x.z,w.z,fmaf(x.w,w.w,a2))));
            w = r3[q]; a3 = fmaf(x.x,w.x,fmaf(x.y,w.y,fmaf(x.z,w.z,fmaf(x.w,w.w,a3))));
            if (extra) { w = r4[q]; a4 = fmaf(x.x,w.x,fmaf(x.y,w.y,fmaf(x.z,w.z,fmaf(x.w,w.w,a4)))); }
        }
        sdbc[ll8][dbc_slot(j8)]      = a0;
        sdbc[ll8][dbc_slot(j8 + 8)]  = a1;
        sdbc[ll8][dbc_slot(j8 + 16)] = a2;
        sdbc[ll8][dbc_slot(j8 + 24)] = a3;
        if (extra) sdbc[ll8][dbc_slot(j8 + 32)] = a4;
    }
    __syncthreads();

    // A3: delta (softplus), delta*xi, g, ybase -> global transposed
    {
        const size_t tile = ((size_t)(c * 32 + b) * 8 + cq) * 4096;
        float dt0 = sdbc[ll8][0], dt1 = sdbc[ll8][1];
        float x3 = sseq4[ll8 + 3];
        float ybp = 0.f;
#pragma unroll 2
        for (int k = 0; k < 8; ++k) {
            int di = j8 * 8 + k;
            float xi = sxi[ll8][di];
            float pre = fmaf(dt0, sdtw[di][0], fmaf(dt1, sdtw[di][1], sdtb[di]));
            float sp = (pre > 20.f) ? pre : __logf(1.f + __expf(pre));
            float zv = fmaf(x3, su[64 + di], sv[64 + di]);
            float g = (zv / (1.f + __expf(-zv))) * swf[di];
            ws[OFF_PD + tile + di * 64 + ll8] = sp;
            ws[OFF_PX + tile + di * 64 + ll8] = sp * xi;
            ws[OFF_PG + tile + di * 64 + ll8] = g;
            ybp = fmaf(g * sD[di], xi, ybp);
        }
        ybp += __shfl_xor(ybp, 1);
        ybp += __shfl_xor(ybp, 2);
        ybp += __shfl_xor(ybp, 4);
        if (j8 == 0) ws[OFF_YB + (size_t)(c * 32 + b) * 512 + gi] = ybp;
    }

    // B/C copy -> [s][t] layout (coalesced over t)
    {
        const size_t bb = ((size_t)(c * 32 + b) * 8 + cq) * 1024;
        for (int i = tid; i < 1024; i += 512) {
            int s = i >> 6, t = i & 63;
            ws[OFF_BCB + bb + i] = sdbc[t][2 + 2 * s];
            ws[OFF_BCC + bb + i] = sdbc[t][3 + 2 * s];
        }
    }
}

// DPP add over 16-lane rows (row_shl). After shl 1,2: lanes s%4==0 hold their
// 4-group sums (zeros shifted in past row end via bound_ctrl).
#define DPP_ADD(v, ctrl) ((v) + __int_as_float(__builtin_amdgcn_update_dpp(0, __float_as_int(v), (ctrl), 0xF, 0xF, true)))

// kscan: pure scan. One block per (c, dquarter, b): 512 blocks x 256 threads.
// r23 change: defer the g-multiply to the fold phase — the scan loop no longer
// reads sg (16 b128 LDS reads/chunk/wave saved) nor multiplies val*gq (64
// VALU/chunk saved); fold applies g via 4 extra b32 reads (2-way bank = free).
__global__ __launch_bounds__(256) void kscan(
    float* __restrict__ ws,
    const float* __restrict__ f_A_log, const float* __restrict__ b_A_log)
{
    const int tid = threadIdx.x;
    const int c  = blockIdx.x >> 7;
    const int dq = (blockIdx.x >> 5) & 3;
    const int b  = blockIdx.x & 31;
    const int dir = c & 1;
    const float* alog = dir ? b_A_log : f_A_log;

    const int dd = tid >> 4;
    const int s  = tid & 15;
    const int d  = dq * 16 + dd;
    const float cA = -expf(alog[d * 16 + s]) * 1.44269504088896340736f;
    float h = 0.f;

    __shared__ float sd[2][16][68], sx[2][16][68], sg[2][16][68];
    __shared__ float sB[2][16][68], sC[2][16][68];
    __shared__ float syT[4][17][68];   // 4 s-group raw partials (no g)
    __shared__ float syb[2][64];

    const int srow = tid >> 4;
    const int scol = (tid & 15) * 4;
    float* ypart = ws + OFF_YPART;
    const size_t cb512 = (size_t)(c * 32 + b) * 512;

    // initial stage: chunk 0 -> buffer 0
    {
        const size_t tb = (size_t)(c * 32 + b) * 8;
        *reinterpret_cast<float4*>(&sd[0][srow][scol]) =
            *reinterpret_cast<const float4*>(ws + OFF_PD + tb * 4096 + dq * 1024 + srow * 64 + scol);
        *reinterpret_cast<float4*>(&sx[0][srow][scol]) =
            *reinterpret_cast<const float4*>(ws + OFF_PX + tb * 4096 + dq * 1024 + srow * 64 + scol);
        *reinterpret_cast<float4*>(&sg[0][srow][scol]) =
            *reinterpret_cast<const float4*>(ws + OFF_PG + tb * 4096 + dq * 1024 + srow * 64 + scol);
        *reinterpret_cast<float4*>(&sB[0][srow][scol]) =
            *reinterpret_cast<const float4*>(ws + OFF_BCB + tb * 1024 + srow * 64 + scol);
        *reinterpret_cast<float4*>(&sC[0][srow][scol]) =
            *reinterpret_cast<const float4*>(ws + OFF_BCC + tb * 1024 + srow * 64 + scol);
        if (dq == 0 && tid < 64) syb[0][tid] = ws[OFF_YB + cb512 + tid];
    }
    __syncthreads();

    for (int chunk = 0; chunk < 8; ++chunk) {
        const int cur = chunk & 1;
        // T14: issue next-chunk prefetch loads to registers.
        float4 nd, nx, ng, nB, nC;
        float nyb = 0.f;
        const bool pf = (chunk < 7);
        if (pf) {
            const size_t tb1 = (size_t)(c * 32 + b) * 8 + chunk + 1;
            nd = *reinterpret_cast<const float4*>(ws + OFF_PD + tb1 * 4096 + dq * 1024 + srow * 64 + scol);
            nx = *reinterpret_cast<const float4*>(ws + OFF_PX + tb1 * 4096 + dq * 1024 + srow * 64 + scol);
            ng = *reinterpret_cast<const float4*>(ws + OFF_PG + tb1 * 4096 + dq * 1024 + srow * 64 + scol);
            nB = *reinterpret_cast<const float4*>(ws + OFF_BCB + tb1 * 1024 + srow * 64 + scol);
            nC = *reinterpret_cast<const float4*>(ws + OFF_BCC + tb1 * 1024 + srow * 64 + scol);
            if (dq == 0 && tid < 64) nyb = ws[OFF_YB + cb512 + (chunk + 1) * 64 + tid];
        }

        // scan 16 m-iters x 4 steps; h carried across chunks.
        // Raw 4-group partials only; g applied in the fold.
        {
#pragma unroll 2
            for (int m = 0; m < 16; ++m) {
                float4 de = *reinterpret_cast<const float4*>(&sd[cur][dd][4 * m]);
                float4 dx = *reinterpret_cast<const float4*>(&sx[cur][dd][4 * m]);
                float4 Bq = *reinterpret_cast<const float4*>(&sB[cur][s][4 * m]);
                float4 Cq = *reinterpret_cast<const float4*>(&sC[cur][s][4 * m]);
                float4 val;
                float a, pc;
                a = exp2f(de.x * cA); h = fmaf(a, h, dx.x * Bq.x); pc = h * Cq.x;
                pc = DPP_ADD(pc, 0x101); pc = DPP_ADD(pc, 0x102);
                val.x = pc;
                a = exp2f(de.y * cA); h = fmaf(a, h, dx.y * Bq.y); pc = h * Cq.y;
                pc = DPP_ADD(pc, 0x101); pc = DPP_ADD(pc, 0x102);
                val.y = pc;
                a = exp2f(de.z * cA); h = fmaf(a, h, dx.z * Bq.z); pc = h * Cq.z;
                pc = DPP_ADD(pc, 0x101); pc = DPP_ADD(pc, 0x102);
                val.z = pc;
                a = exp2f(de.w * cA); h = fmaf(a, h, dx.w * Bq.w); pc = h * Cq.w;
                pc = DPP_ADD(pc, 0x101); pc = DPP_ADD(pc, 0x102);
                val.w = pc;
                if ((s & 3) == 0) *reinterpret_cast<float4*>(&syT[s >> 2][dd][4 * m]) = val;
            }
        }

        // write prefetched chunk into the OTHER buffer (no barrier needed)
        if (pf) {
            *reinterpret_cast<float4*>(&sd[cur ^ 1][srow][scol]) = nd;
            *reinterpret_cast<float4*>(&sx[cur ^ 1][srow][scol]) = nx;
            *reinterpret_cast<float4*>(&sg[cur ^ 1][srow][scol]) = ng;
            *reinterpret_cast<float4*>(&sB[cur ^ 1][srow][scol]) = nB;
            *reinterpret_cast<float4*>(&sC[cur ^ 1][srow][scol]) = nC;
            if (dq == 0 && tid < 64) syb[cur ^ 1][tid] = nyb;
        }
        __syncthreads();

        // fold: per dd, sum 4 s-group partials, multiply by g[dd][t], sum over dd
        {
            const int tt4 = tid >> 2;   // 0..63
            const int j4  = tid & 3;
            float acc = 0.f;
#pragma unroll
            for (int k = 0; k < 4; ++k) {
                const int ddx = j4 * 4 + k;
                float sum4 = syT[0][ddx][tt4] + syT[1][ddx][tt4]
                           + syT[2][ddx][tt4] + syT[3][ddx][tt4];
                acc = fmaf(sum4, sg[cur][ddx][tt4], acc);
            }
            acc += __shfl_xor(acc, 1);
            acc += __shfl_xor(acc, 2);
            if (j4 == 0) {
                int i = chunk * 64 + tt4;
                int l = dir ? (511 - i) : i;
                float res = acc + (dq == 0 ? syb[cur][tt4] : 0.f);
                ypart[((c * 4 + dq) * 32 + b) * 512 + l] = res;
            }
        }
        __syncthreads();
    }
}

__global__ __launch_bounds__(256) void kfinal(const float* __restrict__ xavg,
                                              const float* __restrict__ xmax,
                                              const float* __restrict__ ypart,
                                              const float* __restrict__ gate_w,
                                              const float* __restrict__ gate_b,
                                              const float* __restrict__ out_b,
                                              float* __restrict__ out) {
    const int idx = blockIdx.x * 256 + threadIdx.x;
    float xa = xavg[idx], xm = xmax[idx];
    float alpha = 1.f / (1.f + __expf(-(fmaf(xa, gate_w[0], fmaf(xm, gate_w[1], gate_b[0])))));
    float sa = 0.f, sm = 0.f;
#pragma unroll
    for (int k = 0; k < 8; ++k)  sa += ypart[k * 16384 + idx];
#pragma unroll
    for (int k = 8; k < 16; ++k) sm += ypart[k * 16384 + idx];
    float y = alpha * sa + (1.f - alpha) * sm + out_b[0];
    out[idx] = 1.f / (1.f + __expf(-y));
}

extern "C" void kernel_launch(void* const* d_in, const int* in_sizes, int n_in,
                              void* d_out, int out_size, void* d_ws, size_t ws_size,
                              hipStream_t stream) {
    const float* inp = (const float*)d_in[0];
    const float* paw = (const float*)d_in[1];
    const float* pab = (const float*)d_in[2];
    const float* pmw = (const float*)d_in[3];
    const float* pmb = (const float*)d_in[4];
    const float* gw  = (const float*)d_in[5];
    const float* gb  = (const float*)d_in[6];
    const float* ow  = (const float*)d_in[7];
    const float* ob  = (const float*)d_in[8];

    float* ws = (float*)d_ws;
    float* xavg = ws;
    float* xmax = ws + 16384;
    float* ypart = ws + OFF_YPART;
    float* out = (float*)d_out;

    kreduce<<<16384, 256, 0, stream>>>(inp, xavg, xmax);
    kprep<<<1024, 512, 0, stream>>>(
        xavg, xmax, ws, paw, pab, pmw, pmb, ow,
        (const float*)d_in[9],  (const float*)d_in[10], (const float*)d_in[11], (const float*)d_in[12],
        (const float*)d_in[13], (const float*)d_in[14], (const float*)d_in[16], (const float*)d_in[17],
        (const float*)d_in[18], (const float*)d_in[19], (const float*)d_in[20], (const float*)d_in[21],
        (const float*)d_in[22], (const float*)d_in[23], (const float*)d_in[25], (const float*)d_in[26]);
    kscan<<<512, 256, 0, stream>>>(
        ws, (const float*)d_in[15], (const float*)d_in[24]);
    kfinal<<<64, 256, 0, stream>>>(xavg, xmax, ypart, gw, gb, ob, out);
}